// Round 3
// baseline (1389.916 us; speedup 1.0000x reference)
//
#include <hip/hip_runtime.h>
#include <math.h>

#define BQ   64
#define NN0  2048
#define CF   128
#define ET   2097152
#define OUTF 16

// ---------- helpers ----------
static __device__ __forceinline__ unsigned f2o(float f) {
    // order-preserving transform: a<b (float) <=> f2o(a)<f2o(b) (unsigned)
    unsigned u = __float_as_uint(f);
    return (u & 0x80000000u) ? ~u : (u | 0x80000000u);
}

// ---------- normalize p vectors ----------
__global__ void k_normp(const float* p1, const float* p2, const float* p3, float* pn) {
    const float* ps[3] = {p1, p2, p3};
    const float* p = ps[blockIdx.x];
    int t = threadIdx.x; // 128 threads
    float v = p[t];
    float s = v * v;
    for (int o = 32; o > 0; o >>= 1) s += __shfl_down(s, o);
    __shared__ float ws2[2];
    if ((t & 63) == 0) ws2[t >> 6] = s;
    __syncthreads();
    float tot = ws2[0] + ws2[1];
    pn[blockIdx.x * CF + t] = v / sqrtf(tot);
}

// ---------- GEMM: Y[N][128] = X[N][128] @ W[128][128], f32 ----------
// grid = N/256 blocks, 256 threads. Thread: 16 rows x 8 cols register tile.
__global__ __launch_bounds__(256, 2) void k_gemm(const float* __restrict__ X,
                                                 const float* __restrict__ W,
                                                 float* __restrict__ Y, int N) {
    __shared__ float xT[32][260]; // transposed x chunk, stride 260 keeps float4 align + spreads banks
    __shared__ float Wc[32][128];
    int t = threadIdx.x;
    int cg = t & 15, rg = t >> 4;
    int c0 = cg * 8, r0 = rg * 16;
    int rowBase = blockIdx.x * 256;

    float acc[16][8];
#pragma unroll
    for (int i = 0; i < 16; i++)
#pragma unroll
        for (int j = 0; j < 8; j++) acc[i][j] = 0.f;

    for (int kc = 0; kc < 4; kc++) {
        __syncthreads();
        // stage x tile: 256 rows x 32 k (transposed into xT)
#pragma unroll
        for (int j = 0; j < 8; j++) {
            int id = t + 256 * j;      // 0..2047 float4 slots
            int r = id >> 3;           // row 0..255
            int k4 = id & 7;           // which float4 in the 32-k chunk
            float4 v = *(const float4*)&X[(rowBase + r) * CF + kc * 32 + k4 * 4];
            int kk = k4 * 4;
            xT[kk + 0][r] = v.x; xT[kk + 1][r] = v.y;
            xT[kk + 2][r] = v.z; xT[kk + 3][r] = v.w;
        }
        // stage W chunk: 32 rows x 128 cols
#pragma unroll
        for (int j = 0; j < 4; j++) {
            int id = t + 256 * j;      // 0..1023 float4 slots
            int kk = id >> 5;
            int cc = (id & 31) * 4;
            *(float4*)&Wc[kk][cc] = *(const float4*)&W[(kc * 32 + kk) * CF + cc];
        }
        __syncthreads();
#pragma unroll 4
        for (int kk = 0; kk < 32; kk++) {
            float xr[16];
#pragma unroll
            for (int i = 0; i < 16; i += 4)
                *(float4*)&xr[i] = *(float4*)&xT[kk][r0 + i];
            float wv[8];
            *(float4*)&wv[0] = *(float4*)&Wc[kk][c0];
            *(float4*)&wv[4] = *(float4*)&Wc[kk][c0 + 4];
#pragma unroll
            for (int i = 0; i < 16; i++)
#pragma unroll
                for (int j = 0; j < 8; j++)
                    acc[i][j] = fmaf(xr[i], wv[j], acc[i][j]);
        }
    }
#pragma unroll
    for (int i = 0; i < 16; i++) {
        int r = rowBase + r0 + i;
        *(float4*)&Y[r * CF + c0]     = make_float4(acc[i][0], acc[i][1], acc[i][2], acc[i][3]);
        *(float4*)&Y[r * CF + c0 + 4] = make_float4(acc[i][4], acc[i][5], acc[i][6], acc[i][7]);
    }
}

// ---------- histograms ----------
__global__ void k_hist1(const int* __restrict__ g, const int* __restrict__ dl, int* cnt) {
    int e = blockIdx.x * 256 + threadIdx.x;
    if (e < ET) atomicAdd(&cnt[g[e] * NN0 + dl[e]], 1);
}
__global__ void k_hist2(const int2* __restrict__ edges, const int* pE, int* cnt) {
    int e = blockIdx.x * 256 + threadIdx.x;
    if (e < *pE) atomicAdd(&cnt[edges[e].y], 1);
}

// ---------- exclusive scan (3 kernels), chunk=1024 ----------
__global__ void k_ps1(const int* __restrict__ cnt, int* part) {
    int b = blockIdx.x, t = threadIdx.x;
    int base = b * 1024;
    int s = 0;
    for (int j = t; j < 1024; j += 256) s += cnt[base + j];
    for (int o = 32; o > 0; o >>= 1) s += __shfl_down(s, o);
    __shared__ int sm[4];
    if ((t & 63) == 0) sm[t >> 6] = s;
    __syncthreads();
    if (t == 0) part[b] = sm[0] + sm[1] + sm[2] + sm[3];
}
__global__ void k_ps2(int* part, int nb) {
    if (threadIdx.x == 0) {
        int run = 0;
        for (int i = 0; i < nb; i++) { int v = part[i]; part[i] = run; run += v; }
        part[nb] = run;
    }
}
__global__ void k_ps3(const int* __restrict__ cnt, const int* __restrict__ part,
                      int* rowS, int* curs, int N) {
    __shared__ int sm[256];
    int b = blockIdx.x, t = threadIdx.x;
    int base = b * 1024;
    int loc[4];
    int s = 0;
#pragma unroll
    for (int j = 0; j < 4; j++) { loc[j] = s; s += cnt[base + t * 4 + j]; }
    sm[t] = s;
    __syncthreads();
    for (int o = 1; o < 256; o <<= 1) {
        int u = (t >= o) ? sm[t - o] : 0;
        __syncthreads();
        sm[t] += u;
        __syncthreads();
    }
    int incl = sm[t];
    int thrBase = part[b] + incl - s;
#pragma unroll
    for (int j = 0; j < 4; j++) {
        int idx = base + t * 4 + j;
        rowS[idx] = thrBase + loc[j];
        curs[idx] = thrBase + loc[j];
    }
    if (b == gridDim.x - 1 && t == 255) rowS[N] = part[b] + incl;
}

// ---------- CSR fill ----------
__global__ void k_fill1(const int* __restrict__ g, const int* __restrict__ sl,
                        const int* __restrict__ dl, int* curs, int* csrS) {
    int e = blockIdx.x * 256 + threadIdx.x;
    if (e < ET) {
        int gg = g[e];
        int d = gg * NN0 + dl[e];
        int pos = atomicAdd(&curs[d], 1);
        csrS[pos] = gg * NN0 + sl[e];
    }
}
__global__ void k_fill2(const int2* __restrict__ edges, const int* pE, int* curs, int* csrS) {
    int e = blockIdx.x * 256 + threadIdx.x;
    if (e < *pE) {
        int2 ed = edges[e];
        int pos = atomicAdd(&curs[ed.y], 1);
        csrS[pos] = ed.x;
    }
}

// ---------- GCN aggregation: h[d] = relu(dis_d*sum(dis_s*xw[s]) + xw[d]/deg_d + b) ----------
// one wave per dst node, grid = N/4 blocks of 256; XCD-chunked swizzle for L2 locality
__global__ void k_agg(const float* __restrict__ xw, const int* __restrict__ rowS,
                      const int* __restrict__ csrS, const int* __restrict__ cnt,
                      const float* __restrict__ bias, float* __restrict__ h, int N) {
    int nb = gridDim.x;
    int bid = blockIdx.x;
    int sb = (bid & 7) * (nb >> 3) + (bid >> 3); // contiguous chunk per XCD
    int d = sb * 4 + (threadIdx.x >> 6);
    int lane = threadIdx.x & 63;
    int rs = rowS[d], re = rowS[d + 1];
    float degd = (float)(cnt[d] + 1);
    float disd = rsqrtf(degd);
    float a0 = 0.f, a1 = 0.f;
    for (int j = rs; j < re; j++) {
        int s = csrS[j];
        float diss = rsqrtf((float)(cnt[s] + 1));
        a0 += diss * xw[s * CF + lane];
        a1 += diss * xw[s * CF + 64 + lane];
    }
    float invd = 1.0f / degd;
    float x0 = xw[d * CF + lane], x1 = xw[d * CF + 64 + lane];
    float r0 = disd * a0 + x0 * invd + bias[lane];
    float r1 = disd * a1 + x1 * invd + bias[64 + lane];
    h[d * CF + lane]      = r0 > 0.f ? r0 : 0.f;
    h[d * CF + 64 + lane] = r1 > 0.f ? r1 : 0.f;
}

// ---------- scores: s[i] = tanh(h[i] . pn) ----------
__global__ void k_score(const float* __restrict__ h, const float* __restrict__ pn,
                        float* __restrict__ scores, int N) {
    int wid = (blockIdx.x * 256 + threadIdx.x) >> 6;
    int lane = threadIdx.x & 63;
    float v = h[wid * CF + lane] * pn[lane] + h[wid * CF + 64 + lane] * pn[64 + lane];
    for (int o = 32; o > 0; o >>= 1) v += __shfl_down(v, o);
    if (lane == 0) scores[wid] = tanhf(v);
}

// ---------- exact top-k per graph: map[old global] = new local idx or -1 ----------
__global__ void k_topk(const float* __restrict__ scores, int* __restrict__ map, int n, int k) {
    __shared__ unsigned keys[2048];
    __shared__ int sm[256];
    __shared__ int red[4];
    int b = blockIdx.x, t = threadIdx.x;
    const float* sc = scores + b * n;
    int m = n >> 8; // elements per thread (blocked)

    for (int i = t; i < n; i += 256) keys[i] = f2o(sc[i]);
    __syncthreads();

    // binary search for k-th largest key T
    unsigned prefix = 0u;
    for (int bit = 31; bit >= 0; bit--) {
        unsigned trial = prefix | (1u << bit);
        int c = 0;
        for (int i = t; i < n; i += 256) c += (keys[i] >= trial) ? 1 : 0;
        for (int o = 32; o > 0; o >>= 1) c += __shfl_down(c, o);
        if ((t & 63) == 0) red[t >> 6] = c;
        __syncthreads();
        int tot = red[0] + red[1] + red[2] + red[3];
        __syncthreads();
        if (tot >= k) prefix = trial;
    }
    unsigned T = prefix;

    // count strictly-greater
    int c = 0;
    for (int i = t; i < n; i += 256) c += (keys[i] > T) ? 1 : 0;
    for (int o = 32; o > 0; o >>= 1) c += __shfl_down(c, o);
    if ((t & 63) == 0) red[t >> 6] = c;
    __syncthreads();
    int mEq = k - (red[0] + red[1] + red[2] + red[3]); // #ties to keep (lowest index first)
    __syncthreads();

    // blocked chunk [t*m, t*m+m): rank among ==T elements (index order)
    int base = t * m;
    int eqc = 0;
    for (int j = 0; j < m; j++) eqc += (keys[base + j] == T) ? 1 : 0;
    sm[t] = eqc;
    __syncthreads();
    for (int o = 1; o < 256; o <<= 1) {
        int u = (t >= o) ? sm[t - o] : 0;
        __syncthreads();
        sm[t] += u;
        __syncthreads();
    }
    int er = sm[t] - eqc;
    __syncthreads();

    unsigned kb = 0; int kc = 0;
    for (int j = 0; j < m; j++) {
        unsigned ky = keys[base + j];
        bool kp = (ky > T) || (ky == T && er < mEq);
        if (ky == T) er++;
        if (kp) { kb |= (1u << j); kc++; }
    }
    sm[t] = kc;
    __syncthreads();
    for (int o = 1; o < 256; o <<= 1) {
        int u = (t >= o) ? sm[t - o] : 0;
        __syncthreads();
        sm[t] += u;
        __syncthreads();
    }
    int nidx = sm[t] - kc; // exclusive prefix of kept -> new local index
    for (int j = 0; j < m; j++) {
        map[b * n + base + j] = ((kb >> j) & 1u) ? nidx++ : -1;
    }
}

// ---------- compact kept nodes: xn[g*k+new] = h[old] * score[old] ----------
__global__ void k_compact(const float* __restrict__ h, const float* __restrict__ scores,
                          const int* __restrict__ map, float* __restrict__ xn,
                          int N, int n, int k) {
    int wid = (blockIdx.x * 256 + threadIdx.x) >> 6;
    int lane = threadIdx.x & 63;
    int mi = map[wid];
    if (mi < 0) return;
    float s = scores[wid];
    int gg = wid / n;
    int dst = (gg * k + mi) * CF;
    xn[dst + lane]      = h[wid * CF + lane] * s;
    xn[dst + 64 + lane] = h[wid * CF + 64 + lane] * s;
}

// ---------- edge remap + compaction ----------
__global__ void k_remap1(const int* __restrict__ g, const int* __restrict__ sl,
                         const int* __restrict__ dl, const int* __restrict__ map,
                         int2* __restrict__ eout, int* pCnt, int k) {
    int e = blockIdx.x * 256 + threadIdx.x;
    if (e >= ET) return;
    int gg = g[e];
    int ns = map[gg * NN0 + sl[e]];
    int nd = map[gg * NN0 + dl[e]];
    if (ns >= 0 && nd >= 0) {
        int pos = atomicAdd(pCnt, 1);
        eout[pos] = make_int2(gg * k + ns, gg * k + nd);
    }
}
__global__ void k_remap2(const int2* __restrict__ ein, const int* pE,
                         const int* __restrict__ map, int2* __restrict__ eout,
                         int* pCnt, int n, int k) {
    int e = blockIdx.x * 256 + threadIdx.x;
    if (e >= *pE) return;
    int2 ed = ein[e];
    int ns = map[ed.x], nd = map[ed.y];
    if (ns >= 0 && nd >= 0) {
        int gg = ed.x / n;
        int pos = atomicAdd(pCnt, 1);
        eout[pos] = make_int2(gg * k + ns, gg * k + nd);
    }
}

// ---------- fused layer-3 pool: pooled[b][c] = sum over kept nodes h*score ----------
__global__ void k_pool3(const float* __restrict__ h, const float* __restrict__ scores,
                        const int* __restrict__ map, float* __restrict__ pooled) {
    int b = blockIdx.x, cthr = threadIdx.x; // 128 threads
    float acc = 0.f;
    for (int i = 0; i < 512; i++) {
        int gi = b * 512 + i;
        int mi = map[gi];
        if (mi >= 0) acc += h[gi * CF + cthr] * scores[gi];
    }
    pooled[b * CF + cthr] = acc;
}

// ---------- final MLP: out[b][o] = pooled[b] . Wm[:,o] + bm[o] ----------
__global__ void k_mlp(const float* __restrict__ pooled, const float* __restrict__ Wm,
                      const float* __restrict__ bm, float* __restrict__ out) {
    int b = blockIdx.x, t = threadIdx.x;
    if (t < OUTF) {
        float acc = bm[t];
        for (int c2 = 0; c2 < CF; c2++) acc += pooled[b * CF + c2] * Wm[c2 * OUTF + t];
        out[b * OUTF + t] = acc;
    }
}

extern "C" void kernel_launch(void* const* d_in, const int* in_sizes, int n_in,
                              void* d_out, int out_size, void* d_ws, size_t ws_size,
                              hipStream_t stream) {
    const float* x  = (const float*)d_in[0];
    const int* sl   = (const int*)d_in[1];
    const int* dl   = (const int*)d_in[2];
    const int* g    = (const int*)d_in[3];
    const float* W1 = (const float*)d_in[4];
    const float* b1 = (const float*)d_in[5];
    const float* p1 = (const float*)d_in[6];
    const float* W2 = (const float*)d_in[7];
    const float* b2 = (const float*)d_in[8];
    const float* p2 = (const float*)d_in[9];
    const float* W3 = (const float*)d_in[10];
    const float* b3 = (const float*)d_in[11];
    const float* p3 = (const float*)d_in[12];
    const float* Wm = (const float*)d_in[13];
    const float* bm = (const float*)d_in[14];

    // workspace layout (~138.6 MB total)
    char* ws = (char*)d_ws;
    float* A    = (float*)(ws + 0);            // 64MB
    float* Bb   = (float*)(ws + 67108864ull);  // 64MB
    int*   csrS = (int*)  (ws + 134217728ull); // 8MB
    int*   cnt  = (int*)  (ws + 142606336ull); // 512KB
    int*   rowS = (int*)  (ws + 143130624ull); // 512KB+4
    int*   curs = (int*)  (ws + 143655168ull); // 512KB
    float* scor = (float*)(ws + 144179456ull); // 512KB
    int*   map  = (int*)  (ws + 144703744ull); // 512KB
    float* pn   = (float*)(ws + 145228032ull); // 1.5KB
    float* pool = (float*)(ws + 145230080ull); // 32KB
    int*   ecnt = (int*)  (ws + 145262848ull); // counters
    int*   part = (int*)  (ws + 145263104ull); // scan partials

    // aliased regions (lifetimes verified):
    int2*  EA  = (int2*)(ws + 33554432ull);              // A[32:48MB], lives pool1->csr2 done
    int2*  EB  = (int2*)(ws + 67108864ull);              // Bb[0:16MB], lives pool2->csr3 done
    float* x2  = A;                                      // A[0:32MB]
    float* xw2 = Bb;                                     // Bb[0:32MB]
    float* h2  = A;                                      // A[0:32MB] (x2 dead after gemm2)
    float* x3  = (float*)(ws + 100663296ull);            // Bb[32:48MB]
    float* xw3 = A;                                      // A[0:16MB]
    float* h3  = Bb;                                     // Bb[0:16MB] (EB dead after fill3)

    k_normp<<<3, 128, 0, stream>>>(p1, p2, p3, pn);

    // ================= layer 1 (N=131072, n=2048, k=1024) =================
    k_gemm<<<512, 256, 0, stream>>>(x, W1, A, 131072);
    hipMemsetAsync(cnt, 0, 524288, stream);
    k_hist1<<<8192, 256, 0, stream>>>(g, dl, cnt);
    k_ps1<<<128, 256, 0, stream>>>(cnt, part);
    k_ps2<<<1, 64, 0, stream>>>(part, 128);
    k_ps3<<<128, 256, 0, stream>>>(cnt, part, rowS, curs, 131072);
    k_fill1<<<8192, 256, 0, stream>>>(g, sl, dl, curs, csrS);
    k_agg<<<32768, 256, 0, stream>>>(A, rowS, csrS, cnt, b1, Bb, 131072);
    k_score<<<32768, 256, 0, stream>>>(Bb, pn, scor, 131072);
    k_topk<<<64, 256, 0, stream>>>(scor, map, 2048, 1024);
    k_compact<<<32768, 256, 0, stream>>>(Bb, scor, map, x2, 131072, 2048, 1024);
    hipMemsetAsync(ecnt, 0, 8, stream);
    k_remap1<<<8192, 256, 0, stream>>>(g, sl, dl, map, EA, &ecnt[0], 1024);

    // ================= layer 2 (N=65536, n=1024, k=512) =================
    k_gemm<<<256, 256, 0, stream>>>(x2, W2, xw2, 65536);
    hipMemsetAsync(cnt, 0, 262144, stream);
    k_hist2<<<8192, 256, 0, stream>>>(EA, &ecnt[0], cnt);
    k_ps1<<<64, 256, 0, stream>>>(cnt, part);
    k_ps2<<<1, 64, 0, stream>>>(part, 64);
    k_ps3<<<64, 256, 0, stream>>>(cnt, part, rowS, curs, 65536);
    k_fill2<<<8192, 256, 0, stream>>>(EA, &ecnt[0], curs, csrS);
    k_agg<<<16384, 256, 0, stream>>>(xw2, rowS, csrS, cnt, b2, h2, 65536);
    k_score<<<16384, 256, 0, stream>>>(h2, pn + 128, scor, 65536);
    k_topk<<<64, 256, 0, stream>>>(scor, map, 1024, 512);
    k_compact<<<16384, 256, 0, stream>>>(h2, scor, map, x3, 65536, 1024, 512);
    k_remap2<<<8192, 256, 0, stream>>>(EA, &ecnt[0], map, EB, &ecnt[1], 1024, 512);

    // ================= layer 3 (N=32768, n=512, k=256) =================
    k_gemm<<<128, 256, 0, stream>>>(x3, W3, xw3, 32768);
    hipMemsetAsync(cnt, 0, 131072, stream);
    k_hist2<<<8192, 256, 0, stream>>>(EB, &ecnt[1], cnt);
    k_ps1<<<32, 256, 0, stream>>>(cnt, part);
    k_ps2<<<1, 64, 0, stream>>>(part, 32);
    k_ps3<<<32, 256, 0, stream>>>(cnt, part, rowS, curs, 32768);
    k_fill2<<<8192, 256, 0, stream>>>(EB, &ecnt[1], curs, csrS);
    k_agg<<<8192, 256, 0, stream>>>(xw3, rowS, csrS, cnt, b3, h3, 32768);
    k_score<<<8192, 256, 0, stream>>>(h3, pn + 256, scor, 32768);
    k_topk<<<64, 256, 0, stream>>>(scor, map, 512, 256);
    k_pool3<<<64, 128, 0, stream>>>(h3, scor, map, pool);
    k_mlp<<<64, 64, 0, stream>>>(pool, Wm, bm, (float*)d_out);
}

// Round 4
// 1387.554 us; speedup vs baseline: 1.0017x; 1.0017x over previous
//
#include <hip/hip_runtime.h>
#include <math.h>

#define BQ   64
#define NN0  2048
#define CF   128
#define ET   2097152
#define OUTF 16

// ---------- helpers ----------
static __device__ __forceinline__ unsigned f2o(float f) {
    // order-preserving transform: a<b (float) <=> f2o(a)<f2o(b) (unsigned)
    unsigned u = __float_as_uint(f);
    return (u & 0x80000000u) ? ~u : (u | 0x80000000u);
}

// ---------- normalize p vectors ----------
__global__ void k_normp(const float* p1, const float* p2, const float* p3, float* pn) {
    const float* ps[3] = {p1, p2, p3};
    const float* p = ps[blockIdx.x];
    int t = threadIdx.x; // 128 threads
    float v = p[t];
    float s = v * v;
    for (int o = 32; o > 0; o >>= 1) s += __shfl_down(s, o);
    __shared__ float ws2[2];
    if ((t & 63) == 0) ws2[t >> 6] = s;
    __syncthreads();
    float tot = ws2[0] + ws2[1];
    pn[blockIdx.x * CF + t] = v / sqrtf(tot);
}

// ---------- GEMM: Y[N][128] = X[N][128] @ W[128][128], f32 ----------
// grid = N/256 blocks, 256 threads. Thread: 16 rows x 8 cols register tile.
__global__ __launch_bounds__(256, 2) void k_gemm(const float* __restrict__ X,
                                                 const float* __restrict__ W,
                                                 float* __restrict__ Y, int N) {
    __shared__ float xT[32][260]; // transposed x chunk, stride 260 keeps float4 align + spreads banks
    __shared__ float Wc[32][128];
    int t = threadIdx.x;
    int cg = t & 15, rg = t >> 4;
    int c0 = cg * 8, r0 = rg * 16;
    int rowBase = blockIdx.x * 256;

    float acc[16][8];
#pragma unroll
    for (int i = 0; i < 16; i++)
#pragma unroll
        for (int j = 0; j < 8; j++) acc[i][j] = 0.f;

    for (int kc = 0; kc < 4; kc++) {
        __syncthreads();
        // stage x tile: 256 rows x 32 k (transposed into xT)
#pragma unroll
        for (int j = 0; j < 8; j++) {
            int id = t + 256 * j;      // 0..2047 float4 slots
            int r = id >> 3;           // row 0..255
            int k4 = id & 7;           // which float4 in the 32-k chunk
            float4 v = *(const float4*)&X[(rowBase + r) * CF + kc * 32 + k4 * 4];
            int kk = k4 * 4;
            xT[kk + 0][r] = v.x; xT[kk + 1][r] = v.y;
            xT[kk + 2][r] = v.z; xT[kk + 3][r] = v.w;
        }
        // stage W chunk: 32 rows x 128 cols
#pragma unroll
        for (int j = 0; j < 4; j++) {
            int id = t + 256 * j;      // 0..1023 float4 slots
            int kk = id >> 5;
            int cc = (id & 31) * 4;
            *(float4*)&Wc[kk][cc] = *(const float4*)&W[(kc * 32 + kk) * CF + cc];
        }
        __syncthreads();
#pragma unroll 4
        for (int kk = 0; kk < 32; kk++) {
            float xr[16];
#pragma unroll
            for (int i = 0; i < 16; i += 4)
                *(float4*)&xr[i] = *(float4*)&xT[kk][r0 + i];
            float wv[8];
            *(float4*)&wv[0] = *(float4*)&Wc[kk][c0];
            *(float4*)&wv[4] = *(float4*)&Wc[kk][c0 + 4];
#pragma unroll
            for (int i = 0; i < 16; i++)
#pragma unroll
                for (int j = 0; j < 8; j++)
                    acc[i][j] = fmaf(xr[i], wv[j], acc[i][j]);
        }
    }
#pragma unroll
    for (int i = 0; i < 16; i++) {
        int r = rowBase + r0 + i;
        *(float4*)&Y[r * CF + c0]     = make_float4(acc[i][0], acc[i][1], acc[i][2], acc[i][3]);
        *(float4*)&Y[r * CF + c0 + 4] = make_float4(acc[i][4], acc[i][5], acc[i][6], acc[i][7]);
    }
}

// ---------- histograms ----------
__global__ void k_hist1(const int* __restrict__ g, const int* __restrict__ dl, int* cnt) {
    int e = blockIdx.x * 256 + threadIdx.x;
    if (e < ET) atomicAdd(&cnt[g[e] * NN0 + dl[e]], 1);
}
__global__ void k_hist2(const int2* __restrict__ edges, const int* pE, int* cnt) {
    int e = blockIdx.x * 256 + threadIdx.x;
    if (e < *pE) atomicAdd(&cnt[edges[e].y], 1);
}

// ---------- exclusive scan (3 kernels), chunk=1024 ----------
__global__ void k_ps1(const int* __restrict__ cnt, int* part) {
    int b = blockIdx.x, t = threadIdx.x;
    int base = b * 1024;
    int s = 0;
    for (int j = t; j < 1024; j += 256) s += cnt[base + j];
    for (int o = 32; o > 0; o >>= 1) s += __shfl_down(s, o);
    __shared__ int sm[4];
    if ((t & 63) == 0) sm[t >> 6] = s;
    __syncthreads();
    if (t == 0) part[b] = sm[0] + sm[1] + sm[2] + sm[3];
}
__global__ void k_ps2(int* part, int nb) {
    if (threadIdx.x == 0) {
        int run = 0;
        for (int i = 0; i < nb; i++) { int v = part[i]; part[i] = run; run += v; }
        part[nb] = run;
    }
}
__global__ void k_ps3(const int* __restrict__ cnt, const int* __restrict__ part,
                      int* rowS, int* curs, int N) {
    __shared__ int sm[256];
    int b = blockIdx.x, t = threadIdx.x;
    int base = b * 1024;
    int loc[4];
    int s = 0;
#pragma unroll
    for (int j = 0; j < 4; j++) { loc[j] = s; s += cnt[base + t * 4 + j]; }
    sm[t] = s;
    __syncthreads();
    for (int o = 1; o < 256; o <<= 1) {
        int u = (t >= o) ? sm[t - o] : 0;
        __syncthreads();
        sm[t] += u;
        __syncthreads();
    }
    int incl = sm[t];
    int thrBase = part[b] + incl - s;
#pragma unroll
    for (int j = 0; j < 4; j++) {
        int idx = base + t * 4 + j;
        rowS[idx] = thrBase + loc[j];
        curs[idx] = thrBase + loc[j];
    }
    if (b == gridDim.x - 1 && t == 255) rowS[N] = part[b] + incl;
}

// ---------- CSR fill ----------
__global__ void k_fill1(const int* __restrict__ g, const int* __restrict__ sl,
                        const int* __restrict__ dl, int* curs, int* csrS) {
    int e = blockIdx.x * 256 + threadIdx.x;
    if (e < ET) {
        int gg = g[e];
        int d = gg * NN0 + dl[e];
        int pos = atomicAdd(&curs[d], 1);
        csrS[pos] = gg * NN0 + sl[e];
    }
}
__global__ void k_fill2(const int2* __restrict__ edges, const int* pE, int* curs, int* csrS) {
    int e = blockIdx.x * 256 + threadIdx.x;
    if (e < *pE) {
        int2 ed = edges[e];
        int pos = atomicAdd(&curs[ed.y], 1);
        csrS[pos] = ed.x;
    }
}

// ---------- GCN aggregation: h[d] = relu(dis_d*sum(dis_s*xw[s]) + xw[d]/deg_d + b) ----------
// one wave per dst node, grid = N/4 blocks of 256; XCD-chunked swizzle for L2 locality
__global__ void k_agg(const float* __restrict__ xw, const int* __restrict__ rowS,
                      const int* __restrict__ csrS, const int* __restrict__ cnt,
                      const float* __restrict__ bias, float* __restrict__ h, int N) {
    int nb = gridDim.x;
    int bid = blockIdx.x;
    int sb = (bid & 7) * (nb >> 3) + (bid >> 3); // contiguous chunk per XCD
    int d = sb * 4 + (threadIdx.x >> 6);
    int lane = threadIdx.x & 63;
    int rs = rowS[d], re = rowS[d + 1];
    float degd = (float)(cnt[d] + 1);
    float disd = rsqrtf(degd);
    float a0 = 0.f, a1 = 0.f;
    for (int j = rs; j < re; j++) {
        int s = csrS[j];
        float diss = rsqrtf((float)(cnt[s] + 1));
        a0 += diss * xw[s * CF + lane];
        a1 += diss * xw[s * CF + 64 + lane];
    }
    float invd = 1.0f / degd;
    float x0 = xw[d * CF + lane], x1 = xw[d * CF + 64 + lane];
    float r0 = disd * a0 + x0 * invd + bias[lane];
    float r1 = disd * a1 + x1 * invd + bias[64 + lane];
    h[d * CF + lane]      = r0 > 0.f ? r0 : 0.f;
    h[d * CF + 64 + lane] = r1 > 0.f ? r1 : 0.f;
}

// ---------- scores: s[i] = tanh(h[i] . pn) ----------
__global__ void k_score(const float* __restrict__ h, const float* __restrict__ pn,
                        float* __restrict__ scores, int N) {
    int wid = (blockIdx.x * 256 + threadIdx.x) >> 6;
    int lane = threadIdx.x & 63;
    float v = h[wid * CF + lane] * pn[lane] + h[wid * CF + 64 + lane] * pn[64 + lane];
    for (int o = 32; o > 0; o >>= 1) v += __shfl_down(v, o);
    if (lane == 0) scores[wid] = tanhf(v);
}

// ---------- exact top-k per graph: map[old global] = new local idx or -1 ----------
__global__ void k_topk(const float* __restrict__ scores, int* __restrict__ map, int n, int k) {
    __shared__ unsigned keys[2048];
    __shared__ int sm[256];
    __shared__ int red[4];
    int b = blockIdx.x, t = threadIdx.x;
    const float* sc = scores + b * n;
    int m = n >> 8; // elements per thread (blocked)

    for (int i = t; i < n; i += 256) keys[i] = f2o(sc[i]);
    __syncthreads();

    // binary search for k-th largest key T
    unsigned prefix = 0u;
    for (int bit = 31; bit >= 0; bit--) {
        unsigned trial = prefix | (1u << bit);
        int c = 0;
        for (int i = t; i < n; i += 256) c += (keys[i] >= trial) ? 1 : 0;
        for (int o = 32; o > 0; o >>= 1) c += __shfl_down(c, o);
        if ((t & 63) == 0) red[t >> 6] = c;
        __syncthreads();
        int tot = red[0] + red[1] + red[2] + red[3];
        __syncthreads();
        if (tot >= k) prefix = trial;
    }
    unsigned T = prefix;

    // count strictly-greater
    int c = 0;
    for (int i = t; i < n; i += 256) c += (keys[i] > T) ? 1 : 0;
    for (int o = 32; o > 0; o >>= 1) c += __shfl_down(c, o);
    if ((t & 63) == 0) red[t >> 6] = c;
    __syncthreads();
    int mEq = k - (red[0] + red[1] + red[2] + red[3]); // #ties to keep (lowest index first)
    __syncthreads();

    // blocked chunk [t*m, t*m+m): rank among ==T elements (index order)
    int base = t * m;
    int eqc = 0;
    for (int j = 0; j < m; j++) eqc += (keys[base + j] == T) ? 1 : 0;
    sm[t] = eqc;
    __syncthreads();
    for (int o = 1; o < 256; o <<= 1) {
        int u = (t >= o) ? sm[t - o] : 0;
        __syncthreads();
        sm[t] += u;
        __syncthreads();
    }
    int er = sm[t] - eqc;
    __syncthreads();

    unsigned kb = 0; int kc = 0;
    for (int j = 0; j < m; j++) {
        unsigned ky = keys[base + j];
        bool kp = (ky > T) || (ky == T && er < mEq);
        if (ky == T) er++;
        if (kp) { kb |= (1u << j); kc++; }
    }
    sm[t] = kc;
    __syncthreads();
    for (int o = 1; o < 256; o <<= 1) {
        int u = (t >= o) ? sm[t - o] : 0;
        __syncthreads();
        sm[t] += u;
        __syncthreads();
    }
    int nidx = sm[t] - kc; // exclusive prefix of kept -> new local index
    for (int j = 0; j < m; j++) {
        map[b * n + base + j] = ((kb >> j) & 1u) ? nidx++ : -1;
    }
}

// ---------- compact kept nodes: xn[g*k+new] = h[old] * score[old] ----------
__global__ void k_compact(const float* __restrict__ h, const float* __restrict__ scores,
                          const int* __restrict__ map, float* __restrict__ xn,
                          int N, int n, int k) {
    int wid = (blockIdx.x * 256 + threadIdx.x) >> 6;
    int lane = threadIdx.x & 63;
    int mi = map[wid];
    if (mi < 0) return;
    float s = scores[wid];
    int gg = wid / n;
    int dst = (gg * k + mi) * CF;
    xn[dst + lane]      = h[wid * CF + lane] * s;
    xn[dst + 64 + lane] = h[wid * CF + 64 + lane] * s;
}

// ---------- edge remap + compaction (wave-aggregated atomic) ----------
// R3 fix: single-address atomicAdd per valid edge serialized ~524K L2 round-trips
// (379us, VALUBusy 0.4%). Ballot -> one atomic per wave (64x fewer), per-lane
// offset from lower-lane popcount. Output order still nondeterministic; all
// consumers are order-invariant sums.
__global__ void k_remap1(const int* __restrict__ g, const int* __restrict__ sl,
                         const int* __restrict__ dl, const int* __restrict__ map,
                         int2* __restrict__ eout, int* pCnt, int k) {
    int e = blockIdx.x * 256 + threadIdx.x;
    int lane = threadIdx.x & 63;
    bool valid = false;
    int gg = 0, ns = 0, nd = 0;
    if (e < ET) {
        gg = g[e];
        ns = map[gg * NN0 + sl[e]];
        nd = map[gg * NN0 + dl[e]];
        valid = (ns >= 0 && nd >= 0);
    }
    unsigned long long mask = __ballot(valid);
    int total = __popcll(mask);
    int base = 0;
    if (lane == 0 && total > 0) base = atomicAdd(pCnt, total);
    base = __shfl(base, 0);
    if (valid) {
        int off = __popcll(mask & ((1ull << lane) - 1ull));
        eout[base + off] = make_int2(gg * k + ns, gg * k + nd);
    }
}
__global__ void k_remap2(const int2* __restrict__ ein, const int* pE,
                         const int* __restrict__ map, int2* __restrict__ eout,
                         int* pCnt, int n, int k) {
    int e = blockIdx.x * 256 + threadIdx.x;
    int lane = threadIdx.x & 63;
    bool valid = false;
    int gg = 0, ns = 0, nd = 0;
    if (e < *pE) {
        int2 ed = ein[e];
        ns = map[ed.x]; nd = map[ed.y];
        gg = ed.x / n;
        valid = (ns >= 0 && nd >= 0);
    }
    unsigned long long mask = __ballot(valid);
    int total = __popcll(mask);
    int base = 0;
    if (lane == 0 && total > 0) base = atomicAdd(pCnt, total);
    base = __shfl(base, 0);
    if (valid) {
        int off = __popcll(mask & ((1ull << lane) - 1ull));
        eout[base + off] = make_int2(gg * k + ns, gg * k + nd);
    }
}

// ---------- fused layer-3 pool: pooled[b][c] = sum over kept nodes h*score ----------
__global__ void k_pool3(const float* __restrict__ h, const float* __restrict__ scores,
                        const int* __restrict__ map, float* __restrict__ pooled) {
    int b = blockIdx.x, cthr = threadIdx.x; // 128 threads
    float acc = 0.f;
    for (int i = 0; i < 512; i++) {
        int gi = b * 512 + i;
        int mi = map[gi];
        if (mi >= 0) acc += h[gi * CF + cthr] * scores[gi];
    }
    pooled[b * CF + cthr] = acc;
}

// ---------- final MLP: out[b][o] = pooled[b] . Wm[:,o] + bm[o] ----------
__global__ void k_mlp(const float* __restrict__ pooled, const float* __restrict__ Wm,
                      const float* __restrict__ bm, float* __restrict__ out) {
    int b = blockIdx.x, t = threadIdx.x;
    if (t < OUTF) {
        float acc = bm[t];
        for (int c2 = 0; c2 < CF; c2++) acc += pooled[b * CF + c2] * Wm[c2 * OUTF + t];
        out[b * OUTF + t] = acc;
    }
}

extern "C" void kernel_launch(void* const* d_in, const int* in_sizes, int n_in,
                              void* d_out, int out_size, void* d_ws, size_t ws_size,
                              hipStream_t stream) {
    const float* x  = (const float*)d_in[0];
    const int* sl   = (const int*)d_in[1];
    const int* dl   = (const int*)d_in[2];
    const int* g    = (const int*)d_in[3];
    const float* W1 = (const float*)d_in[4];
    const float* b1 = (const float*)d_in[5];
    const float* p1 = (const float*)d_in[6];
    const float* W2 = (const float*)d_in[7];
    const float* b2 = (const float*)d_in[8];
    const float* p2 = (const float*)d_in[9];
    const float* W3 = (const float*)d_in[10];
    const float* b3 = (const float*)d_in[11];
    const float* p3 = (const float*)d_in[12];
    const float* Wm = (const float*)d_in[13];
    const float* bm = (const float*)d_in[14];

    // workspace layout (~138.6 MB total)
    char* ws = (char*)d_ws;
    float* A    = (float*)(ws + 0);            // 64MB
    float* Bb   = (float*)(ws + 67108864ull);  // 64MB
    int*   csrS = (int*)  (ws + 134217728ull); // 8MB
    int*   cnt  = (int*)  (ws + 142606336ull); // 512KB
    int*   rowS = (int*)  (ws + 143130624ull); // 512KB+4
    int*   curs = (int*)  (ws + 143655168ull); // 512KB
    float* scor = (float*)(ws + 144179456ull); // 512KB
    int*   map  = (int*)  (ws + 144703744ull); // 512KB
    float* pn   = (float*)(ws + 145228032ull); // 1.5KB
    float* pool = (float*)(ws + 145230080ull); // 32KB
    int*   ecnt = (int*)  (ws + 145262848ull); // counters
    int*   part = (int*)  (ws + 145263104ull); // scan partials

    // aliased regions (lifetimes verified):
    int2*  EA  = (int2*)(ws + 33554432ull);              // A[32:48MB], lives pool1->csr2 done
    int2*  EB  = (int2*)(ws + 67108864ull);              // Bb[0:16MB], lives pool2->csr3 done
    float* x2  = A;                                      // A[0:32MB]
    float* xw2 = Bb;                                     // Bb[0:32MB]
    float* h2  = A;                                      // A[0:32MB] (x2 dead after gemm2)
    float* x3  = (float*)(ws + 100663296ull);            // Bb[32:48MB]
    float* xw3 = A;                                      // A[0:16MB]
    float* h3  = Bb;                                     // Bb[0:16MB] (EB dead after fill3)

    k_normp<<<3, 128, 0, stream>>>(p1, p2, p3, pn);

    // ================= layer 1 (N=131072, n=2048, k=1024) =================
    k_gemm<<<512, 256, 0, stream>>>(x, W1, A, 131072);
    hipMemsetAsync(cnt, 0, 524288, stream);
    k_hist1<<<8192, 256, 0, stream>>>(g, dl, cnt);
    k_ps1<<<128, 256, 0, stream>>>(cnt, part);
    k_ps2<<<1, 64, 0, stream>>>(part, 128);
    k_ps3<<<128, 256, 0, stream>>>(cnt, part, rowS, curs, 131072);
    k_fill1<<<8192, 256, 0, stream>>>(g, sl, dl, curs, csrS);
    k_agg<<<32768, 256, 0, stream>>>(A, rowS, csrS, cnt, b1, Bb, 131072);
    k_score<<<32768, 256, 0, stream>>>(Bb, pn, scor, 131072);
    k_topk<<<64, 256, 0, stream>>>(scor, map, 2048, 1024);
    k_compact<<<32768, 256, 0, stream>>>(Bb, scor, map, x2, 131072, 2048, 1024);
    hipMemsetAsync(ecnt, 0, 8, stream);
    k_remap1<<<8192, 256, 0, stream>>>(g, sl, dl, map, EA, &ecnt[0], 1024);

    // ================= layer 2 (N=65536, n=1024, k=512) =================
    k_gemm<<<256, 256, 0, stream>>>(x2, W2, xw2, 65536);
    hipMemsetAsync(cnt, 0, 262144, stream);
    k_hist2<<<8192, 256, 0, stream>>>(EA, &ecnt[0], cnt);
    k_ps1<<<64, 256, 0, stream>>>(cnt, part);
    k_ps2<<<1, 64, 0, stream>>>(part, 64);
    k_ps3<<<64, 256, 0, stream>>>(cnt, part, rowS, curs, 65536);
    k_fill2<<<8192, 256, 0, stream>>>(EA, &ecnt[0], curs, csrS);
    k_agg<<<16384, 256, 0, stream>>>(xw2, rowS, csrS, cnt, b2, h2, 65536);
    k_score<<<16384, 256, 0, stream>>>(h2, pn + 128, scor, 65536);
    k_topk<<<64, 256, 0, stream>>>(scor, map, 1024, 512);
    k_compact<<<16384, 256, 0, stream>>>(h2, scor, map, x3, 65536, 1024, 512);
    k_remap2<<<8192, 256, 0, stream>>>(EA, &ecnt[0], map, EB, &ecnt[1], 1024, 512);

    // ================= layer 3 (N=32768, n=512, k=256) =================
    k_gemm<<<128, 256, 0, stream>>>(x3, W3, xw3, 32768);
    hipMemsetAsync(cnt, 0, 131072, stream);
    k_hist2<<<8192, 256, 0, stream>>>(EB, &ecnt[1], cnt);
    k_ps1<<<32, 256, 0, stream>>>(cnt, part);
    k_ps2<<<1, 64, 0, stream>>>(part, 32);
    k_ps3<<<32, 256, 0, stream>>>(cnt, part, rowS, curs, 32768);
    k_fill2<<<8192, 256, 0, stream>>>(EB, &ecnt[1], curs, csrS);
    k_agg<<<8192, 256, 0, stream>>>(xw3, rowS, csrS, cnt, b3, h3, 32768);
    k_score<<<8192, 256, 0, stream>>>(h3, pn + 256, scor, 32768);
    k_topk<<<64, 256, 0, stream>>>(scor, map, 512, 256);
    k_pool3<<<64, 128, 0, stream>>>(h3, scor, map, pool);
    k_mlp<<<64, 64, 0, stream>>>(pool, Wm, bm, (float*)d_out);
}

// Round 6
// 974.079 us; speedup vs baseline: 1.4269x; 1.4245x over previous
//
#include <hip/hip_runtime.h>
#include <math.h>

#define BQ   64
#define NN0  2048
#define CF   128
#define ET   2097152
#define OUTF 16

// ---------- helpers ----------
static __device__ __forceinline__ unsigned f2o(float f) {
    // order-preserving transform: a<b (float) <=> f2o(a)<f2o(b) (unsigned)
    unsigned u = __float_as_uint(f);
    return (u & 0x80000000u) ? ~u : (u | 0x80000000u);
}

// ---------- normalize p vectors ----------
__global__ void k_normp(const float* p1, const float* p2, const float* p3, float* pn) {
    const float* ps[3] = {p1, p2, p3};
    const float* p = ps[blockIdx.x];
    int t = threadIdx.x; // 128 threads
    float v = p[t];
    float s = v * v;
    for (int o = 32; o > 0; o >>= 1) s += __shfl_down(s, o);
    __shared__ float ws2[2];
    if ((t & 63) == 0) ws2[t >> 6] = s;
    __syncthreads();
    float tot = ws2[0] + ws2[1];
    pn[blockIdx.x * CF + t] = v / sqrtf(tot);
}

// ---------- GEMM: Y[N][128] = X[N][128] @ W[128][128], f32 ----------
// grid = N/256 blocks, 256 threads. Thread: 16 rows x 8 cols register tile.
__global__ __launch_bounds__(256, 2) void k_gemm(const float* __restrict__ X,
                                                 const float* __restrict__ W,
                                                 float* __restrict__ Y, int N) {
    __shared__ float xT[32][260]; // transposed x chunk, stride 260 keeps float4 align + spreads banks
    __shared__ float Wc[32][128];
    int t = threadIdx.x;
    int cg = t & 15, rg = t >> 4;
    int c0 = cg * 8, r0 = rg * 16;
    int rowBase = blockIdx.x * 256;

    float acc[16][8];
#pragma unroll
    for (int i = 0; i < 16; i++)
#pragma unroll
        for (int j = 0; j < 8; j++) acc[i][j] = 0.f;

    for (int kc = 0; kc < 4; kc++) {
        __syncthreads();
        // stage x tile: 256 rows x 32 k (transposed into xT)
#pragma unroll
        for (int j = 0; j < 8; j++) {
            int id = t + 256 * j;      // 0..2047 float4 slots
            int r = id >> 3;           // row 0..255
            int k4 = id & 7;           // which float4 in the 32-k chunk
            float4 v = *(const float4*)&X[(rowBase + r) * CF + kc * 32 + k4 * 4];
            int kk = k4 * 4;
            xT[kk + 0][r] = v.x; xT[kk + 1][r] = v.y;
            xT[kk + 2][r] = v.z; xT[kk + 3][r] = v.w;
        }
        // stage W chunk: 32 rows x 128 cols
#pragma unroll
        for (int j = 0; j < 4; j++) {
            int id = t + 256 * j;      // 0..1023 float4 slots
            int kk = id >> 5;
            int cc = (id & 31) * 4;
            *(float4*)&Wc[kk][cc] = *(const float4*)&W[(kc * 32 + kk) * CF + cc];
        }
        __syncthreads();
#pragma unroll 4
        for (int kk = 0; kk < 32; kk++) {
            float xr[16];
#pragma unroll
            for (int i = 0; i < 16; i += 4)
                *(float4*)&xr[i] = *(float4*)&xT[kk][r0 + i];
            float wv[8];
            *(float4*)&wv[0] = *(float4*)&Wc[kk][c0];
            *(float4*)&wv[4] = *(float4*)&Wc[kk][c0 + 4];
#pragma unroll
            for (int i = 0; i < 16; i++)
#pragma unroll
                for (int j = 0; j < 8; j++)
                    acc[i][j] = fmaf(xr[i], wv[j], acc[i][j]);
        }
    }
#pragma unroll
    for (int i = 0; i < 16; i++) {
        int r = rowBase + r0 + i;
        *(float4*)&Y[r * CF + c0]     = make_float4(acc[i][0], acc[i][1], acc[i][2], acc[i][3]);
        *(float4*)&Y[r * CF + c0 + 4] = make_float4(acc[i][4], acc[i][5], acc[i][6], acc[i][7]);
    }
}

// ---------- histograms ----------
__global__ void k_hist1(const int* __restrict__ g, const int* __restrict__ dl, int* cnt) {
    int e = blockIdx.x * 256 + threadIdx.x;
    if (e < ET) atomicAdd(&cnt[g[e] * NN0 + dl[e]], 1);
}
__global__ void k_hist2(const int2* __restrict__ edges, const int* pE, int* cnt) {
    int e = blockIdx.x * 256 + threadIdx.x;
    if (e < *pE) atomicAdd(&cnt[edges[e].y], 1);
}

// ---------- exclusive scan (3 kernels), chunk=1024 ----------
__global__ void k_ps1(const int* __restrict__ cnt, int* part) {
    int b = blockIdx.x, t = threadIdx.x;
    int base = b * 1024;
    int s = 0;
    for (int j = t; j < 1024; j += 256) s += cnt[base + j];
    for (int o = 32; o > 0; o >>= 1) s += __shfl_down(s, o);
    __shared__ int sm[4];
    if ((t & 63) == 0) sm[t >> 6] = s;
    __syncthreads();
    if (t == 0) part[b] = sm[0] + sm[1] + sm[2] + sm[3];
}
__global__ void k_ps2(int* part, int nb) {
    if (threadIdx.x == 0) {
        int run = 0;
        for (int i = 0; i < nb; i++) { int v = part[i]; part[i] = run; run += v; }
        part[nb] = run;
    }
}
__global__ void k_ps3(const int* __restrict__ cnt, const int* __restrict__ part,
                      int* rowS, int* curs, int N) {
    __shared__ int sm[256];
    int b = blockIdx.x, t = threadIdx.x;
    int base = b * 1024;
    int loc[4];
    int s = 0;
#pragma unroll
    for (int j = 0; j < 4; j++) { loc[j] = s; s += cnt[base + t * 4 + j]; }
    sm[t] = s;
    __syncthreads();
    for (int o = 1; o < 256; o <<= 1) {
        int u = (t >= o) ? sm[t - o] : 0;
        __syncthreads();
        sm[t] += u;
        __syncthreads();
    }
    int incl = sm[t];
    int thrBase = part[b] + incl - s;
#pragma unroll
    for (int j = 0; j < 4; j++) {
        int idx = base + t * 4 + j;
        rowS[idx] = thrBase + loc[j];
        curs[idx] = thrBase + loc[j];
    }
    if (b == gridDim.x - 1 && t == 255) rowS[N] = part[b] + incl;
}

// ---------- CSR fill ----------
__global__ void k_fill1(const int* __restrict__ g, const int* __restrict__ sl,
                        const int* __restrict__ dl, int* curs, int* csrS) {
    int e = blockIdx.x * 256 + threadIdx.x;
    if (e < ET) {
        int gg = g[e];
        int d = gg * NN0 + dl[e];
        int pos = atomicAdd(&curs[d], 1);
        csrS[pos] = gg * NN0 + sl[e];
    }
}
__global__ void k_fill2(const int2* __restrict__ edges, const int* pE, int* curs, int* csrS) {
    int e = blockIdx.x * 256 + threadIdx.x;
    if (e < *pE) {
        int2 ed = edges[e];
        int pos = atomicAdd(&curs[ed.y], 1);
        csrS[pos] = ed.x;
    }
}

// ---------- GCN aggregation: h[d] = relu(dis_d*sum(dis_s*xw[s]) + xw[d]/deg_d + b) ----------
// one wave per dst node, grid = N/4 blocks of 256; XCD-chunked swizzle for L2 locality
__global__ void k_agg(const float* __restrict__ xw, const int* __restrict__ rowS,
                      const int* __restrict__ csrS, const int* __restrict__ cnt,
                      const float* __restrict__ bias, float* __restrict__ h, int N) {
    int nb = gridDim.x;
    int bid = blockIdx.x;
    int sb = (bid & 7) * (nb >> 3) + (bid >> 3); // contiguous chunk per XCD
    int d = sb * 4 + (threadIdx.x >> 6);
    int lane = threadIdx.x & 63;
    int rs = rowS[d], re = rowS[d + 1];
    float degd = (float)(cnt[d] + 1);
    float disd = rsqrtf(degd);
    float a0 = 0.f, a1 = 0.f;
    for (int j = rs; j < re; j++) {
        int s = csrS[j];
        float diss = rsqrtf((float)(cnt[s] + 1));
        a0 += diss * xw[s * CF + lane];
        a1 += diss * xw[s * CF + 64 + lane];
    }
    float invd = 1.0f / degd;
    float x0 = xw[d * CF + lane], x1 = xw[d * CF + 64 + lane];
    float r0 = disd * a0 + x0 * invd + bias[lane];
    float r1 = disd * a1 + x1 * invd + bias[64 + lane];
    h[d * CF + lane]      = r0 > 0.f ? r0 : 0.f;
    h[d * CF + 64 + lane] = r1 > 0.f ? r1 : 0.f;
}

// ---------- scores: s[i] = tanh(h[i] . pn) ----------
__global__ void k_score(const float* __restrict__ h, const float* __restrict__ pn,
                        float* __restrict__ scores, int N) {
    int wid = (blockIdx.x * 256 + threadIdx.x) >> 6;
    int lane = threadIdx.x & 63;
    float v = h[wid * CF + lane] * pn[lane] + h[wid * CF + 64 + lane] * pn[64 + lane];
    for (int o = 32; o > 0; o >>= 1) v += __shfl_down(v, o);
    if (lane == 0) scores[wid] = tanhf(v);
}

// ---------- exact top-k per graph: map[old global] = new local idx or -1 ----------
__global__ void k_topk(const float* __restrict__ scores, int* __restrict__ map, int n, int k) {
    __shared__ unsigned keys[2048];
    __shared__ int sm[256];
    __shared__ int red[4];
    int b = blockIdx.x, t = threadIdx.x;
    const float* sc = scores + b * n;
    int m = n >> 8; // elements per thread (blocked)

    for (int i = t; i < n; i += 256) keys[i] = f2o(sc[i]);
    __syncthreads();

    // binary search for k-th largest key T
    unsigned prefix = 0u;
    for (int bit = 31; bit >= 0; bit--) {
        unsigned trial = prefix | (1u << bit);
        int c = 0;
        for (int i = t; i < n; i += 256) c += (keys[i] >= trial) ? 1 : 0;
        for (int o = 32; o > 0; o >>= 1) c += __shfl_down(c, o);
        if ((t & 63) == 0) red[t >> 6] = c;
        __syncthreads();
        int tot = red[0] + red[1] + red[2] + red[3];
        __syncthreads();
        if (tot >= k) prefix = trial;
    }
    unsigned T = prefix;

    // count strictly-greater
    int c = 0;
    for (int i = t; i < n; i += 256) c += (keys[i] > T) ? 1 : 0;
    for (int o = 32; o > 0; o >>= 1) c += __shfl_down(c, o);
    if ((t & 63) == 0) red[t >> 6] = c;
    __syncthreads();
    int mEq = k - (red[0] + red[1] + red[2] + red[3]); // #ties to keep (lowest index first)
    __syncthreads();

    // blocked chunk [t*m, t*m+m): rank among ==T elements (index order)
    int base = t * m;
    int eqc = 0;
    for (int j = 0; j < m; j++) eqc += (keys[base + j] == T) ? 1 : 0;
    sm[t] = eqc;
    __syncthreads();
    for (int o = 1; o < 256; o <<= 1) {
        int u = (t >= o) ? sm[t - o] : 0;
        __syncthreads();
        sm[t] += u;
        __syncthreads();
    }
    int er = sm[t] - eqc;
    __syncthreads();

    unsigned kb = 0; int kc = 0;
    for (int j = 0; j < m; j++) {
        unsigned ky = keys[base + j];
        bool kp = (ky > T) || (ky == T && er < mEq);
        if (ky == T) er++;
        if (kp) { kb |= (1u << j); kc++; }
    }
    sm[t] = kc;
    __syncthreads();
    for (int o = 1; o < 256; o <<= 1) {
        int u = (t >= o) ? sm[t - o] : 0;
        __syncthreads();
        sm[t] += u;
        __syncthreads();
    }
    int nidx = sm[t] - kc; // exclusive prefix of kept -> new local index
    for (int j = 0; j < m; j++) {
        map[b * n + base + j] = ((kb >> j) & 1u) ? nidx++ : -1;
    }
}

// ---------- compact kept nodes: xn[g*k+new] = h[old] * score[old] ----------
__global__ void k_compact(const float* __restrict__ h, const float* __restrict__ scores,
                          const int* __restrict__ map, float* __restrict__ xn,
                          int N, int n, int k) {
    int wid = (blockIdx.x * 256 + threadIdx.x) >> 6;
    int lane = threadIdx.x & 63;
    int mi = map[wid];
    if (mi < 0) return;
    float s = scores[wid];
    int gg = wid / n;
    int dst = (gg * k + mi) * CF;
    xn[dst + lane]      = h[wid * CF + lane] * s;
    xn[dst + 64 + lane] = h[wid * CF + 64 + lane] * s;
}

// ---------- edge remap + compaction, atomic-free two-pass ----------
// R4 post-mortem: wave-aggregated atomic == per-lane atomic (379us both) because
// the compiler already wave-aggregates; limiter is ~32K serialized same-address
// device-scope atomics (~12ns each at the coherence point). Fix: ballot ->
// per-wave count array -> exclusive scan -> write at computed offsets. Zero
// atomics, deterministic edge order.
__global__ void k_remapA1(const int* __restrict__ g, const int* __restrict__ sl,
                          const int* __restrict__ dl, const int* __restrict__ map,
                          int* __restrict__ wcnt) {
    int e = blockIdx.x * 256 + threadIdx.x;
    int gg = g[e];
    bool valid = (map[gg * NN0 + sl[e]] >= 0) && (map[gg * NN0 + dl[e]] >= 0);
    unsigned long long mask = __ballot(valid);
    if ((threadIdx.x & 63) == 0) wcnt[e >> 6] = __popcll(mask);
}
__global__ void k_remapB1(const int* __restrict__ g, const int* __restrict__ sl,
                          const int* __restrict__ dl, const int* __restrict__ map,
                          const int* __restrict__ wbase, int2* __restrict__ eout,
                          int* __restrict__ pTot, int k) {
    int e = blockIdx.x * 256 + threadIdx.x;
    int lane = threadIdx.x & 63;
    int gg = g[e];
    int ns = map[gg * NN0 + sl[e]];
    int nd = map[gg * NN0 + dl[e]];
    bool valid = (ns >= 0 && nd >= 0);
    unsigned long long mask = __ballot(valid);
    if (valid) {
        int off = __popcll(mask & ((1ull << lane) - 1ull));
        eout[wbase[e >> 6] + off] = make_int2(gg * k + ns, gg * k + nd);
    }
    if (e == 0) pTot[0] = wbase[ET >> 6];
}
__global__ void k_remapA2(const int2* __restrict__ ein, const int* pE,
                          const int* __restrict__ map, int* __restrict__ wcnt) {
    int e = blockIdx.x * 256 + threadIdx.x;
    bool valid = false;
    if (e < *pE) {
        int2 ed = ein[e];
        valid = (map[ed.x] >= 0) && (map[ed.y] >= 0);
    }
    unsigned long long mask = __ballot(valid);
    if ((threadIdx.x & 63) == 0) wcnt[e >> 6] = __popcll(mask);
}
__global__ void k_remapB2(const int2* __restrict__ ein, const int* pE,
                          const int* __restrict__ map, const int* __restrict__ wbase,
                          int2* __restrict__ eout, int* __restrict__ pTot,
                          int n, int k) {
    int e = blockIdx.x * 256 + threadIdx.x;
    int lane = threadIdx.x & 63;
    bool valid = false;
    int gg = 0, ns = 0, nd = 0;
    if (e < *pE) {
        int2 ed = ein[e];
        ns = map[ed.x]; nd = map[ed.y];
        gg = ed.x / n;
        valid = (ns >= 0 && nd >= 0);
    }
    unsigned long long mask = __ballot(valid);
    if (valid) {
        int off = __popcll(mask & ((1ull << lane) - 1ull));
        eout[wbase[e >> 6] + off] = make_int2(gg * k + ns, gg * k + nd);
    }
    if (e == 0) pTot[0] = wbase[ET >> 6];
}

// ---------- fused layer-3 pool: pooled[b][c] = sum over kept nodes h*score ----------
__global__ void k_pool3(const float* __restrict__ h, const float* __restrict__ scores,
                        const int* __restrict__ map, float* __restrict__ pooled) {
    int b = blockIdx.x, cthr = threadIdx.x; // 128 threads
    float acc = 0.f;
    for (int i = 0; i < 512; i++) {
        int gi = b * 512 + i;
        int mi = map[gi];
        if (mi >= 0) acc += h[gi * CF + cthr] * scores[gi];
    }
    pooled[b * CF + cthr] = acc;
}

// ---------- final MLP: out[b][o] = pooled[b] . Wm[:,o] + bm[o] ----------
__global__ void k_mlp(const float* __restrict__ pooled, const float* __restrict__ Wm,
                      const float* __restrict__ bm, float* __restrict__ out) {
    int b = blockIdx.x, t = threadIdx.x;
    if (t < OUTF) {
        float acc = bm[t];
        for (int c2 = 0; c2 < CF; c2++) acc += pooled[b * CF + c2] * Wm[c2 * OUTF + t];
        out[b * OUTF + t] = acc;
    }
}

extern "C" void kernel_launch(void* const* d_in, const int* in_sizes, int n_in,
                              void* d_out, int out_size, void* d_ws, size_t ws_size,
                              hipStream_t stream) {
    const float* x  = (const float*)d_in[0];
    const int* sl   = (const int*)d_in[1];
    const int* dl   = (const int*)d_in[2];
    const int* g    = (const int*)d_in[3];
    const float* W1 = (const float*)d_in[4];
    const float* b1 = (const float*)d_in[5];
    const float* p1 = (const float*)d_in[6];
    const float* W2 = (const float*)d_in[7];
    const float* b2 = (const float*)d_in[8];
    const float* p2 = (const float*)d_in[9];
    const float* W3 = (const float*)d_in[10];
    const float* b3 = (const float*)d_in[11];
    const float* p3 = (const float*)d_in[12];
    const float* Wm = (const float*)d_in[13];
    const float* bm = (const float*)d_in[14];

    // workspace layout (~145.3 MB total)
    char* ws = (char*)d_ws;
    float* A    = (float*)(ws + 0);            // 64MB
    float* Bb   = (float*)(ws + 67108864ull);  // 64MB
    int*   csrS = (int*)  (ws + 134217728ull); // 8MB
    int*   cnt  = (int*)  (ws + 142606336ull); // 512KB
    int*   rowS = (int*)  (ws + 143130624ull); // 512KB+4
    int*   curs = (int*)  (ws + 143655168ull); // 512KB
    float* scor = (float*)(ws + 144179456ull); // 512KB
    int*   map  = (int*)  (ws + 144703744ull); // 512KB
    float* pn   = (float*)(ws + 145228032ull); // 1.5KB
    float* pool = (float*)(ws + 145230080ull); // 32KB
    int*   ecnt = (int*)  (ws + 145262848ull); // counters
    int*   part = (int*)  (ws + 145263104ull); // scan partials (<=129 ints)

    // aliased regions (lifetimes verified):
    int2*  EA  = (int2*)(ws + 33554432ull);              // A[32:48MB], lives pool1->csr2 done
    int2*  EB  = (int2*)(ws + 67108864ull);              // Bb[0:16MB], lives pool2->csr3 done
    float* x2  = A;                                      // A[0:32MB]
    float* xw2 = Bb;                                     // Bb[0:32MB]
    float* h2  = A;                                      // A[0:32MB] (x2 dead after gemm2)
    float* x3  = (float*)(ws + 100663296ull);            // Bb[32:48MB]
    float* xw3 = A;                                      // A[0:16MB]
    float* h3  = Bb;                                     // Bb[0:16MB] (EB dead after fill3)
    // wave-count scratch for remap two-pass: A[48:64MB] (xw1 dead there after agg1;
    // untouched by x2/EA/h2; dead before gemm3 reuses A[0:16])
    int*   wcnt  = (int*)(ws + 50331648ull);             // 32768 ints
    int*   wbase = (int*)(ws + 50462720ull);             // 32769 ints

    k_normp<<<3, 128, 0, stream>>>(p1, p2, p3, pn);

    // ================= layer 1 (N=131072, n=2048, k=1024) =================
    k_gemm<<<512, 256, 0, stream>>>(x, W1, A, 131072);
    hipMemsetAsync(cnt, 0, 524288, stream);
    k_hist1<<<8192, 256, 0, stream>>>(g, dl, cnt);
    k_ps1<<<128, 256, 0, stream>>>(cnt, part);
    k_ps2<<<1, 64, 0, stream>>>(part, 128);
    k_ps3<<<128, 256, 0, stream>>>(cnt, part, rowS, curs, 131072);
    k_fill1<<<8192, 256, 0, stream>>>(g, sl, dl, curs, csrS);
    k_agg<<<32768, 256, 0, stream>>>(A, rowS, csrS, cnt, b1, Bb, 131072);
    k_score<<<32768, 256, 0, stream>>>(Bb, pn, scor, 131072);
    k_topk<<<64, 256, 0, stream>>>(scor, map, 2048, 1024);
    k_compact<<<32768, 256, 0, stream>>>(Bb, scor, map, x2, 131072, 2048, 1024);
    k_remapA1<<<8192, 256, 0, stream>>>(g, sl, dl, map, wcnt);
    k_ps1<<<32, 256, 0, stream>>>(wcnt, part);
    k_ps2<<<1, 64, 0, stream>>>(part, 32);
    k_ps3<<<32, 256, 0, stream>>>(wcnt, part, wbase, wbase, 32768);
    k_remapB1<<<8192, 256, 0, stream>>>(g, sl, dl, map, wbase, EA, &ecnt[0], 1024);

    // ================= layer 2 (N=65536, n=1024, k=512) =================
    k_gemm<<<256, 256, 0, stream>>>(x2, W2, xw2, 65536);
    hipMemsetAsync(cnt, 0, 262144, stream);
    k_hist2<<<8192, 256, 0, stream>>>(EA, &ecnt[0], cnt);
    k_ps1<<<64, 256, 0, stream>>>(cnt, part);
    k_ps2<<<1, 64, 0, stream>>>(part, 64);
    k_ps3<<<64, 256, 0, stream>>>(cnt, part, rowS, curs, 65536);
    k_fill2<<<8192, 256, 0, stream>>>(EA, &ecnt[0], curs, csrS);
    k_agg<<<16384, 256, 0, stream>>>(xw2, rowS, csrS, cnt, b2, h2, 65536);
    k_score<<<16384, 256, 0, stream>>>(h2, pn + 128, scor, 65536);
    k_topk<<<64, 256, 0, stream>>>(scor, map, 1024, 512);
    k_compact<<<16384, 256, 0, stream>>>(h2, scor, map, x3, 65536, 1024, 512);
    k_remapA2<<<8192, 256, 0, stream>>>(EA, &ecnt[0], map, wcnt);
    k_ps1<<<32, 256, 0, stream>>>(wcnt, part);
    k_ps2<<<1, 64, 0, stream>>>(part, 32);
    k_ps3<<<32, 256, 0, stream>>>(wcnt, part, wbase, wbase, 32768);
    k_remapB2<<<8192, 256, 0, stream>>>(EA, &ecnt[0], map, wbase, EB, &ecnt[1], 1024, 512);

    // ================= layer 3 (N=32768, n=512, k=256) =================
    k_gemm<<<128, 256, 0, stream>>>(x3, W3, xw3, 32768);
    hipMemsetAsync(cnt, 0, 131072, stream);
    k_hist2<<<8192, 256, 0, stream>>>(EB, &ecnt[1], cnt);
    k_ps1<<<32, 256, 0, stream>>>(cnt, part);
    k_ps2<<<1, 64, 0, stream>>>(part, 32);
    k_ps3<<<32, 256, 0, stream>>>(cnt, part, rowS, curs, 32768);
    k_fill2<<<8192, 256, 0, stream>>>(EB, &ecnt[1], curs, csrS);
    k_agg<<<8192, 256, 0, stream>>>(xw3, rowS, csrS, cnt, b3, h3, 32768);
    k_score<<<8192, 256, 0, stream>>>(h3, pn + 256, scor, 32768);
    k_topk<<<64, 256, 0, stream>>>(scor, map, 512, 256);
    k_pool3<<<64, 128, 0, stream>>>(h3, scor, map, pool);
    k_mlp<<<64, 64, 0, stream>>>(pool, Wm, bm, (float*)d_out);
}

// Round 7
// 920.444 us; speedup vs baseline: 1.5101x; 1.0583x over previous
//
#include <hip/hip_runtime.h>
#include <math.h>

#define BQ   64
#define NN0  2048
#define CF   128
#define ET   2097152
#define OUTF 16

// ---------- helpers ----------
static __device__ __forceinline__ unsigned f2o(float f) {
    // order-preserving transform: a<b (float) <=> f2o(a)<f2o(b) (unsigned)
    unsigned u = __float_as_uint(f);
    return (u & 0x80000000u) ? ~u : (u | 0x80000000u);
}

// ---------- normalize p vectors ----------
__global__ void k_normp(const float* p1, const float* p2, const float* p3, float* pn) {
    const float* ps[3] = {p1, p2, p3};
    const float* p = ps[blockIdx.x];
    int t = threadIdx.x; // 128 threads
    float v = p[t];
    float s = v * v;
    for (int o = 32; o > 0; o >>= 1) s += __shfl_down(s, o);
    __shared__ float ws2[2];
    if ((t & 63) == 0) ws2[t >> 6] = s;
    __syncthreads();
    float tot = ws2[0] + ws2[1];
    pn[blockIdx.x * CF + t] = v / sqrtf(tot);
}

// ---------- GEMM: Y[N][128] = X[N][128] @ W[128][128], f32 ----------
// grid = N/256 blocks, 256 threads. Thread: 16 rows x 8 cols register tile.
__global__ __launch_bounds__(256, 2) void k_gemm(const float* __restrict__ X,
                                                 const float* __restrict__ W,
                                                 float* __restrict__ Y, int N) {
    __shared__ float xT[32][260]; // transposed x chunk, stride 260 keeps float4 align + spreads banks
    __shared__ float Wc[32][128];
    int t = threadIdx.x;
    int cg = t & 15, rg = t >> 4;
    int c0 = cg * 8, r0 = rg * 16;
    int rowBase = blockIdx.x * 256;

    float acc[16][8];
#pragma unroll
    for (int i = 0; i < 16; i++)
#pragma unroll
        for (int j = 0; j < 8; j++) acc[i][j] = 0.f;

    for (int kc = 0; kc < 4; kc++) {
        __syncthreads();
        // stage x tile: 256 rows x 32 k (transposed into xT)
#pragma unroll
        for (int j = 0; j < 8; j++) {
            int id = t + 256 * j;      // 0..2047 float4 slots
            int r = id >> 3;           // row 0..255
            int k4 = id & 7;           // which float4 in the 32-k chunk
            float4 v = *(const float4*)&X[(rowBase + r) * CF + kc * 32 + k4 * 4];
            int kk = k4 * 4;
            xT[kk + 0][r] = v.x; xT[kk + 1][r] = v.y;
            xT[kk + 2][r] = v.z; xT[kk + 3][r] = v.w;
        }
        // stage W chunk: 32 rows x 128 cols
#pragma unroll
        for (int j = 0; j < 4; j++) {
            int id = t + 256 * j;      // 0..1023 float4 slots
            int kk = id >> 5;
            int cc = (id & 31) * 4;
            *(float4*)&Wc[kk][cc] = *(const float4*)&W[(kc * 32 + kk) * CF + cc];
        }
        __syncthreads();
#pragma unroll 4
        for (int kk = 0; kk < 32; kk++) {
            float xr[16];
#pragma unroll
            for (int i = 0; i < 16; i += 4)
                *(float4*)&xr[i] = *(float4*)&xT[kk][r0 + i];
            float wv[8];
            *(float4*)&wv[0] = *(float4*)&Wc[kk][c0];
            *(float4*)&wv[4] = *(float4*)&Wc[kk][c0 + 4];
#pragma unroll
            for (int i = 0; i < 16; i++)
#pragma unroll
                for (int j = 0; j < 8; j++)
                    acc[i][j] = fmaf(xr[i], wv[j], acc[i][j]);
        }
    }
#pragma unroll
    for (int i = 0; i < 16; i++) {
        int r = rowBase + r0 + i;
        *(float4*)&Y[r * CF + c0]     = make_float4(acc[i][0], acc[i][1], acc[i][2], acc[i][3]);
        *(float4*)&Y[r * CF + c0 + 4] = make_float4(acc[i][4], acc[i][5], acc[i][6], acc[i][7]);
    }
}

// ---------- histograms ----------
__global__ void k_hist1(const int* __restrict__ g, const int* __restrict__ dl, int* cnt) {
    int e = blockIdx.x * 256 + threadIdx.x;
    if (e < ET) atomicAdd(&cnt[g[e] * NN0 + dl[e]], 1);
}
__global__ void k_hist2(const int2* __restrict__ edges, const int* pE, int* cnt) {
    int e = blockIdx.x * 256 + threadIdx.x;
    if (e < *pE) atomicAdd(&cnt[edges[e].y], 1);
}

// ---------- exclusive scan (3 kernels), chunk=1024 ----------
__global__ void k_ps1(const int* __restrict__ cnt, int* part) {
    int b = blockIdx.x, t = threadIdx.x;
    int base = b * 1024;
    int s = 0;
    for (int j = t; j < 1024; j += 256) s += cnt[base + j];
    for (int o = 32; o > 0; o >>= 1) s += __shfl_down(s, o);
    __shared__ int sm[4];
    if ((t & 63) == 0) sm[t >> 6] = s;
    __syncthreads();
    if (t == 0) part[b] = sm[0] + sm[1] + sm[2] + sm[3];
}
__global__ void k_ps2(int* part, int nb) {
    if (threadIdx.x == 0) {
        int run = 0;
        for (int i = 0; i < nb; i++) { int v = part[i]; part[i] = run; run += v; }
        part[nb] = run;
    }
}
__global__ void k_ps3(const int* __restrict__ cnt, const int* __restrict__ part,
                      int* rowS, int* curs, int N) {
    __shared__ int sm[256];
    int b = blockIdx.x, t = threadIdx.x;
    int base = b * 1024;
    int loc[4];
    int s = 0;
#pragma unroll
    for (int j = 0; j < 4; j++) { loc[j] = s; s += cnt[base + t * 4 + j]; }
    sm[t] = s;
    __syncthreads();
    for (int o = 1; o < 256; o <<= 1) {
        int u = (t >= o) ? sm[t - o] : 0;
        __syncthreads();
        sm[t] += u;
        __syncthreads();
    }
    int incl = sm[t];
    int thrBase = part[b] + incl - s;
#pragma unroll
    for (int j = 0; j < 4; j++) {
        int idx = base + t * 4 + j;
        rowS[idx] = thrBase + loc[j];
        curs[idx] = thrBase + loc[j];
    }
    if (b == gridDim.x - 1 && t == 255) rowS[N] = part[b] + incl;
}

// ---------- CSR fill, XCD-range-partitioned ----------
// R6 post-mortem: scattered 4B csrS stores from random XCDs => one partial-line
// HBM writeback per edge (WRITE_SIZE 135MB ~= 2M x 64B, 157us). Fix: block
// bid handles edge-chunk (bid>>3) for dst-range (bid&7); bid%8 ~ XCD, so each
// XCD writes only its ~1MB csrS window -> lines accumulate in local L2, one
// writeback per line. g/dl re-read 8x but 7/8 passes hit the shared 256MB L3.
__global__ void k_fill1(const int* __restrict__ g, const int* __restrict__ sl,
                        const int* __restrict__ dl, int* curs, int* csrS) {
    int r = blockIdx.x & 7;
    int base = (blockIdx.x >> 3) * 2048; // 1024 chunks x 2048 edges = ET
#pragma unroll
    for (int i = 0; i < 8; i++) {
        int e = base + i * 256 + threadIdx.x;
        int gg = g[e];
        int d = gg * NN0 + dl[e];
        if ((d >> 14) == r) { // 131072/8 = 16384-node ranges
            int pos = atomicAdd(&curs[d], 1);
            csrS[pos] = gg * NN0 + sl[e];
        }
    }
}
__global__ void k_fill2(const int2* __restrict__ edges, const int* pE,
                        int* curs, int* csrS, int shift) {
    int r = blockIdx.x & 7;
    int base = (blockIdx.x >> 3) * 2048;
    int E = *pE;
#pragma unroll
    for (int i = 0; i < 8; i++) {
        int e = base + i * 256 + threadIdx.x;
        if (e < E) {
            int2 ed = edges[e];
            if ((ed.y >> shift) == r) {
                int pos = atomicAdd(&curs[ed.y], 1);
                csrS[pos] = ed.x;
            }
        }
    }
}

// ---------- GCN aggregation: h[d] = relu(dis_d*sum(dis_s*xw[s]) + xw[d]/deg_d + b) ----------
// one wave per dst node, grid = N/4 blocks of 256; XCD-chunked swizzle for L2 locality
__global__ void k_agg(const float* __restrict__ xw, const int* __restrict__ rowS,
                      const int* __restrict__ csrS, const int* __restrict__ cnt,
                      const float* __restrict__ bias, float* __restrict__ h, int N) {
    int nb = gridDim.x;
    int bid = blockIdx.x;
    int sb = (bid & 7) * (nb >> 3) + (bid >> 3); // contiguous chunk per XCD
    int d = sb * 4 + (threadIdx.x >> 6);
    int lane = threadIdx.x & 63;
    int rs = rowS[d], re = rowS[d + 1];
    float degd = (float)(cnt[d] + 1);
    float disd = rsqrtf(degd);
    float a0 = 0.f, a1 = 0.f;
    for (int j = rs; j < re; j++) {
        int s = csrS[j];
        float diss = rsqrtf((float)(cnt[s] + 1));
        a0 += diss * xw[s * CF + lane];
        a1 += diss * xw[s * CF + 64 + lane];
    }
    float invd = 1.0f / degd;
    float x0 = xw[d * CF + lane], x1 = xw[d * CF + 64 + lane];
    float r0 = disd * a0 + x0 * invd + bias[lane];
    float r1 = disd * a1 + x1 * invd + bias[64 + lane];
    h[d * CF + lane]      = r0 > 0.f ? r0 : 0.f;
    h[d * CF + 64 + lane] = r1 > 0.f ? r1 : 0.f;
}

// ---------- scores: s[i] = tanh(h[i] . pn) ----------
__global__ void k_score(const float* __restrict__ h, const float* __restrict__ pn,
                        float* __restrict__ scores, int N) {
    int wid = (blockIdx.x * 256 + threadIdx.x) >> 6;
    int lane = threadIdx.x & 63;
    float v = h[wid * CF + lane] * pn[lane] + h[wid * CF + 64 + lane] * pn[64 + lane];
    for (int o = 32; o > 0; o >>= 1) v += __shfl_down(v, o);
    if (lane == 0) scores[wid] = tanhf(v);
}

// ---------- exact top-k per graph: map[old global] = new local idx or -1 ----------
__global__ void k_topk(const float* __restrict__ scores, int* __restrict__ map, int n, int k) {
    __shared__ unsigned keys[2048];
    __shared__ int sm[256];
    __shared__ int red[4];
    int b = blockIdx.x, t = threadIdx.x;
    const float* sc = scores + b * n;
    int m = n >> 8; // elements per thread (blocked)

    for (int i = t; i < n; i += 256) keys[i] = f2o(sc[i]);
    __syncthreads();

    // binary search for k-th largest key T
    unsigned prefix = 0u;
    for (int bit = 31; bit >= 0; bit--) {
        unsigned trial = prefix | (1u << bit);
        int c = 0;
        for (int i = t; i < n; i += 256) c += (keys[i] >= trial) ? 1 : 0;
        for (int o = 32; o > 0; o >>= 1) c += __shfl_down(c, o);
        if ((t & 63) == 0) red[t >> 6] = c;
        __syncthreads();
        int tot = red[0] + red[1] + red[2] + red[3];
        __syncthreads();
        if (tot >= k) prefix = trial;
    }
    unsigned T = prefix;

    // count strictly-greater
    int c = 0;
    for (int i = t; i < n; i += 256) c += (keys[i] > T) ? 1 : 0;
    for (int o = 32; o > 0; o >>= 1) c += __shfl_down(c, o);
    if ((t & 63) == 0) red[t >> 6] = c;
    __syncthreads();
    int mEq = k - (red[0] + red[1] + red[2] + red[3]); // #ties to keep (lowest index first)
    __syncthreads();

    // blocked chunk [t*m, t*m+m): rank among ==T elements (index order)
    int base = t * m;
    int eqc = 0;
    for (int j = 0; j < m; j++) eqc += (keys[base + j] == T) ? 1 : 0;
    sm[t] = eqc;
    __syncthreads();
    for (int o = 1; o < 256; o <<= 1) {
        int u = (t >= o) ? sm[t - o] : 0;
        __syncthreads();
        sm[t] += u;
        __syncthreads();
    }
    int er = sm[t] - eqc;
    __syncthreads();

    unsigned kb = 0; int kc = 0;
    for (int j = 0; j < m; j++) {
        unsigned ky = keys[base + j];
        bool kp = (ky > T) || (ky == T && er < mEq);
        if (ky == T) er++;
        if (kp) { kb |= (1u << j); kc++; }
    }
    sm[t] = kc;
    __syncthreads();
    for (int o = 1; o < 256; o <<= 1) {
        int u = (t >= o) ? sm[t - o] : 0;
        __syncthreads();
        sm[t] += u;
        __syncthreads();
    }
    int nidx = sm[t] - kc; // exclusive prefix of kept -> new local index
    for (int j = 0; j < m; j++) {
        map[b * n + base + j] = ((kb >> j) & 1u) ? nidx++ : -1;
    }
}

// ---------- compact kept nodes: xn[g*k+new] = h[old] * score[old] ----------
__global__ void k_compact(const float* __restrict__ h, const float* __restrict__ scores,
                          const int* __restrict__ map, float* __restrict__ xn,
                          int N, int n, int k) {
    int wid = (blockIdx.x * 256 + threadIdx.x) >> 6;
    int lane = threadIdx.x & 63;
    int mi = map[wid];
    if (mi < 0) return;
    float s = scores[wid];
    int gg = wid / n;
    int dst = (gg * k + mi) * CF;
    xn[dst + lane]      = h[wid * CF + lane] * s;
    xn[dst + 64 + lane] = h[wid * CF + 64 + lane] * s;
}

// ---------- edge remap + compaction, atomic-free two-pass ----------
// (R4/R6: shared-counter atomics removed; ballot -> wave counts -> scan ->
// offset writes. Deterministic edge order.)
__global__ void k_remapA1(const int* __restrict__ g, const int* __restrict__ sl,
                          const int* __restrict__ dl, const int* __restrict__ map,
                          int* __restrict__ wcnt) {
    int e = blockIdx.x * 256 + threadIdx.x;
    int gg = g[e];
    bool valid = (map[gg * NN0 + sl[e]] >= 0) && (map[gg * NN0 + dl[e]] >= 0);
    unsigned long long mask = __ballot(valid);
    if ((threadIdx.x & 63) == 0) wcnt[e >> 6] = __popcll(mask);
}
__global__ void k_remapB1(const int* __restrict__ g, const int* __restrict__ sl,
                          const int* __restrict__ dl, const int* __restrict__ map,
                          const int* __restrict__ wbase, int2* __restrict__ eout,
                          int* __restrict__ pTot, int k) {
    int e = blockIdx.x * 256 + threadIdx.x;
    int lane = threadIdx.x & 63;
    int gg = g[e];
    int ns = map[gg * NN0 + sl[e]];
    int nd = map[gg * NN0 + dl[e]];
    bool valid = (ns >= 0 && nd >= 0);
    unsigned long long mask = __ballot(valid);
    if (valid) {
        int off = __popcll(mask & ((1ull << lane) - 1ull));
        eout[wbase[e >> 6] + off] = make_int2(gg * k + ns, gg * k + nd);
    }
    if (e == 0) pTot[0] = wbase[ET >> 6];
}
__global__ void k_remapA2(const int2* __restrict__ ein, const int* pE,
                          const int* __restrict__ map, int* __restrict__ wcnt) {
    int e = blockIdx.x * 256 + threadIdx.x;
    bool valid = false;
    if (e < *pE) {
        int2 ed = ein[e];
        valid = (map[ed.x] >= 0) && (map[ed.y] >= 0);
    }
    unsigned long long mask = __ballot(valid);
    if ((threadIdx.x & 63) == 0) wcnt[e >> 6] = __popcll(mask);
}
__global__ void k_remapB2(const int2* __restrict__ ein, const int* pE,
                          const int* __restrict__ map, const int* __restrict__ wbase,
                          int2* __restrict__ eout, int* __restrict__ pTot,
                          int n, int k) {
    int e = blockIdx.x * 256 + threadIdx.x;
    int lane = threadIdx.x & 63;
    bool valid = false;
    int gg = 0, ns = 0, nd = 0;
    if (e < *pE) {
        int2 ed = ein[e];
        ns = map[ed.x]; nd = map[ed.y];
        gg = ed.x / n;
        valid = (ns >= 0 && nd >= 0);
    }
    unsigned long long mask = __ballot(valid);
    if (valid) {
        int off = __popcll(mask & ((1ull << lane) - 1ull));
        eout[wbase[e >> 6] + off] = make_int2(gg * k + ns, gg * k + nd);
    }
    if (e == 0) pTot[0] = wbase[ET >> 6];
}

// ---------- fused layer-3 pool: pooled[b][c] = sum over kept nodes h*score ----------
__global__ void k_pool3(const float* __restrict__ h, const float* __restrict__ scores,
                        const int* __restrict__ map, float* __restrict__ pooled) {
    int b = blockIdx.x, cthr = threadIdx.x; // 128 threads
    float acc = 0.f;
    for (int i = 0; i < 512; i++) {
        int gi = b * 512 + i;
        int mi = map[gi];
        if (mi >= 0) acc += h[gi * CF + cthr] * scores[gi];
    }
    pooled[b * CF + cthr] = acc;
}

// ---------- final MLP: out[b][o] = pooled[b] . Wm[:,o] + bm[o] ----------
__global__ void k_mlp(const float* __restrict__ pooled, const float* __restrict__ Wm,
                      const float* __restrict__ bm, float* __restrict__ out) {
    int b = blockIdx.x, t = threadIdx.x;
    if (t < OUTF) {
        float acc = bm[t];
        for (int c2 = 0; c2 < CF; c2++) acc += pooled[b * CF + c2] * Wm[c2 * OUTF + t];
        out[b * OUTF + t] = acc;
    }
}

extern "C" void kernel_launch(void* const* d_in, const int* in_sizes, int n_in,
                              void* d_out, int out_size, void* d_ws, size_t ws_size,
                              hipStream_t stream) {
    const float* x  = (const float*)d_in[0];
    const int* sl   = (const int*)d_in[1];
    const int* dl   = (const int*)d_in[2];
    const int* g    = (const int*)d_in[3];
    const float* W1 = (const float*)d_in[4];
    const float* b1 = (const float*)d_in[5];
    const float* p1 = (const float*)d_in[6];
    const float* W2 = (const float*)d_in[7];
    const float* b2 = (const float*)d_in[8];
    const float* p2 = (const float*)d_in[9];
    const float* W3 = (const float*)d_in[10];
    const float* b3 = (const float*)d_in[11];
    const float* p3 = (const float*)d_in[12];
    const float* Wm = (const float*)d_in[13];
    const float* bm = (const float*)d_in[14];

    // workspace layout (~145.3 MB total)
    char* ws = (char*)d_ws;
    float* A    = (float*)(ws + 0);            // 64MB
    float* Bb   = (float*)(ws + 67108864ull);  // 64MB
    int*   csrS = (int*)  (ws + 134217728ull); // 8MB
    int*   cnt  = (int*)  (ws + 142606336ull); // 512KB
    int*   rowS = (int*)  (ws + 143130624ull); // 512KB+4
    int*   curs = (int*)  (ws + 143655168ull); // 512KB
    float* scor = (float*)(ws + 144179456ull); // 512KB
    int*   map  = (int*)  (ws + 144703744ull); // 512KB
    float* pn   = (float*)(ws + 145228032ull); // 1.5KB
    float* pool = (float*)(ws + 145230080ull); // 32KB
    int*   ecnt = (int*)  (ws + 145262848ull); // counters
    int*   part = (int*)  (ws + 145263104ull); // scan partials (<=129 ints)

    // aliased regions (lifetimes verified):
    int2*  EA  = (int2*)(ws + 33554432ull);              // A[32:48MB], lives pool1->csr2 done
    int2*  EB  = (int2*)(ws + 67108864ull);              // Bb[0:16MB], lives pool2->csr3 done
    float* x2  = A;                                      // A[0:32MB]
    float* xw2 = Bb;                                     // Bb[0:32MB]
    float* h2  = A;                                      // A[0:32MB] (x2 dead after gemm2)
    float* x3  = (float*)(ws + 100663296ull);            // Bb[32:48MB]
    float* xw3 = A;                                      // A[0:16MB]
    float* h3  = Bb;                                     // Bb[0:16MB] (EB dead after fill3)
    // wave-count scratch for remap two-pass: A[48:64MB] (xw1 dead there after agg1;
    // untouched by x2/EA/h2; dead before gemm3 reuses A[0:16])
    int*   wcnt  = (int*)(ws + 50331648ull);             // 32768 ints
    int*   wbase = (int*)(ws + 50462720ull);             // 32769 ints

    k_normp<<<3, 128, 0, stream>>>(p1, p2, p3, pn);

    // ================= layer 1 (N=131072, n=2048, k=1024) =================
    k_gemm<<<512, 256, 0, stream>>>(x, W1, A, 131072);
    hipMemsetAsync(cnt, 0, 524288, stream);
    k_hist1<<<8192, 256, 0, stream>>>(g, dl, cnt);
    k_ps1<<<128, 256, 0, stream>>>(cnt, part);
    k_ps2<<<1, 64, 0, stream>>>(part, 128);
    k_ps3<<<128, 256, 0, stream>>>(cnt, part, rowS, curs, 131072);
    k_fill1<<<8192, 256, 0, stream>>>(g, sl, dl, curs, csrS);
    k_agg<<<32768, 256, 0, stream>>>(A, rowS, csrS, cnt, b1, Bb, 131072);
    k_score<<<32768, 256, 0, stream>>>(Bb, pn, scor, 131072);
    k_topk<<<64, 256, 0, stream>>>(scor, map, 2048, 1024);
    k_compact<<<32768, 256, 0, stream>>>(Bb, scor, map, x2, 131072, 2048, 1024);
    k_remapA1<<<8192, 256, 0, stream>>>(g, sl, dl, map, wcnt);
    k_ps1<<<32, 256, 0, stream>>>(wcnt, part);
    k_ps2<<<1, 64, 0, stream>>>(part, 32);
    k_ps3<<<32, 256, 0, stream>>>(wcnt, part, wbase, wbase, 32768);
    k_remapB1<<<8192, 256, 0, stream>>>(g, sl, dl, map, wbase, EA, &ecnt[0], 1024);

    // ================= layer 2 (N=65536, n=1024, k=512) =================
    k_gemm<<<256, 256, 0, stream>>>(x2, W2, xw2, 65536);
    hipMemsetAsync(cnt, 0, 262144, stream);
    k_hist2<<<8192, 256, 0, stream>>>(EA, &ecnt[0], cnt);
    k_ps1<<<64, 256, 0, stream>>>(cnt, part);
    k_ps2<<<1, 64, 0, stream>>>(part, 64);
    k_ps3<<<64, 256, 0, stream>>>(cnt, part, rowS, curs, 65536);
    k_fill2<<<8192, 256, 0, stream>>>(EA, &ecnt[0], curs, csrS, 13);
    k_agg<<<16384, 256, 0, stream>>>(xw2, rowS, csrS, cnt, b2, h2, 65536);
    k_score<<<16384, 256, 0, stream>>>(h2, pn + 128, scor, 65536);
    k_topk<<<64, 256, 0, stream>>>(scor, map, 1024, 512);
    k_compact<<<16384, 256, 0, stream>>>(h2, scor, map, x3, 65536, 1024, 512);
    k_remapA2<<<8192, 256, 0, stream>>>(EA, &ecnt[0], map, wcnt);
    k_ps1<<<32, 256, 0, stream>>>(wcnt, part);
    k_ps2<<<1, 64, 0, stream>>>(part, 32);
    k_ps3<<<32, 256, 0, stream>>>(wcnt, part, wbase, wbase, 32768);
    k_remapB2<<<8192, 256, 0, stream>>>(EA, &ecnt[0], map, wbase, EB, &ecnt[1], 1024, 512);

    // ================= layer 3 (N=32768, n=512, k=256) =================
    k_gemm<<<128, 256, 0, stream>>>(x3, W3, xw3, 32768);
    hipMemsetAsync(cnt, 0, 131072, stream);
    k_hist2<<<8192, 256, 0, stream>>>(EB, &ecnt[1], cnt);
    k_ps1<<<32, 256, 0, stream>>>(cnt, part);
    k_ps2<<<1, 64, 0, stream>>>(part, 32);
    k_ps3<<<32, 256, 0, stream>>>(cnt, part, rowS, curs, 32768);
    k_fill2<<<8192, 256, 0, stream>>>(EB, &ecnt[1], curs, csrS, 12);
    k_agg<<<8192, 256, 0, stream>>>(xw3, rowS, csrS, cnt, b3, h3, 32768);
    k_score<<<8192, 256, 0, stream>>>(h3, pn + 256, scor, 32768);
    k_topk<<<64, 256, 0, stream>>>(scor, map, 512, 256);
    k_pool3<<<64, 128, 0, stream>>>(h3, scor, map, pool);
    k_mlp<<<64, 64, 0, stream>>>(pool, Wm, bm, (float*)d_out);
}

// Round 8
// 875.516 us; speedup vs baseline: 1.5875x; 1.0513x over previous
//
#include <hip/hip_runtime.h>
#include <math.h>

#define BQ   64
#define NN0  2048
#define CF   128
#define ET   2097152
#define OUTF 16

// ---------- helpers ----------
static __device__ __forceinline__ unsigned f2o(float f) {
    unsigned u = __float_as_uint(f);
    return (u & 0x80000000u) ? ~u : (u | 0x80000000u);
}

// ---------- normalize p vectors ----------
__global__ void k_normp(const float* p1, const float* p2, const float* p3, float* pn) {
    const float* ps[3] = {p1, p2, p3};
    const float* p = ps[blockIdx.x];
    int t = threadIdx.x; // 128 threads
    float v = p[t];
    float s = v * v;
    for (int o = 32; o > 0; o >>= 1) s += __shfl_down(s, o);
    __shared__ float ws2[2];
    if ((t & 63) == 0) ws2[t >> 6] = s;
    __syncthreads();
    float tot = ws2[0] + ws2[1];
    pn[blockIdx.x * CF + t] = v / sqrtf(tot);
}

// ---------- GEMM: Y[N][128] = X[N][128] @ W[128][128], f32 ----------
__global__ __launch_bounds__(256, 2) void k_gemm(const float* __restrict__ X,
                                                 const float* __restrict__ W,
                                                 float* __restrict__ Y, int N) {
    __shared__ float xT[32][260];
    __shared__ float Wc[32][128];
    int t = threadIdx.x;
    int cg = t & 15, rg = t >> 4;
    int c0 = cg * 8, r0 = rg * 16;
    int rowBase = blockIdx.x * 256;

    float acc[16][8];
#pragma unroll
    for (int i = 0; i < 16; i++)
#pragma unroll
        for (int j = 0; j < 8; j++) acc[i][j] = 0.f;

    for (int kc = 0; kc < 4; kc++) {
        __syncthreads();
#pragma unroll
        for (int j = 0; j < 8; j++) {
            int id = t + 256 * j;
            int r = id >> 3;
            int k4 = id & 7;
            float4 v = *(const float4*)&X[(rowBase + r) * CF + kc * 32 + k4 * 4];
            int kk = k4 * 4;
            xT[kk + 0][r] = v.x; xT[kk + 1][r] = v.y;
            xT[kk + 2][r] = v.z; xT[kk + 3][r] = v.w;
        }
#pragma unroll
        for (int j = 0; j < 4; j++) {
            int id = t + 256 * j;
            int kk = id >> 5;
            int cc = (id & 31) * 4;
            *(float4*)&Wc[kk][cc] = *(const float4*)&W[(kc * 32 + kk) * CF + cc];
        }
        __syncthreads();
#pragma unroll 4
        for (int kk = 0; kk < 32; kk++) {
            float xr[16];
#pragma unroll
            for (int i = 0; i < 16; i += 4)
                *(float4*)&xr[i] = *(float4*)&xT[kk][r0 + i];
            float wv[8];
            *(float4*)&wv[0] = *(float4*)&Wc[kk][c0];
            *(float4*)&wv[4] = *(float4*)&Wc[kk][c0 + 4];
#pragma unroll
            for (int i = 0; i < 16; i++)
#pragma unroll
                for (int j = 0; j < 8; j++)
                    acc[i][j] = fmaf(xr[i], wv[j], acc[i][j]);
        }
    }
#pragma unroll
    for (int i = 0; i < 16; i++) {
        int r = rowBase + r0 + i;
        *(float4*)&Y[r * CF + c0]     = make_float4(acc[i][0], acc[i][1], acc[i][2], acc[i][3]);
        *(float4*)&Y[r * CF + c0 + 4] = make_float4(acc[i][4], acc[i][5], acc[i][6], acc[i][7]);
    }
}

// ---------- histograms ----------
__global__ void k_hist1(const int* __restrict__ g, const int* __restrict__ dl, int* cnt) {
    int e = blockIdx.x * 256 + threadIdx.x;
    if (e < ET) atomicAdd(&cnt[g[e] * NN0 + dl[e]], 1);
}
__global__ void k_hist2(const int2* __restrict__ edges, const int* pE, int* cnt) {
    int e = blockIdx.x * 256 + threadIdx.x;
    if (e < *pE) atomicAdd(&cnt[edges[e].y], 1);
}

// ---------- exclusive scan (3 kernels), chunk=1024 ----------
__global__ void k_ps1(const int* __restrict__ cnt, int* part) {
    int b = blockIdx.x, t = threadIdx.x;
    int base = b * 1024;
    int s = 0;
    for (int j = t; j < 1024; j += 256) s += cnt[base + j];
    for (int o = 32; o > 0; o >>= 1) s += __shfl_down(s, o);
    __shared__ int sm[4];
    if ((t & 63) == 0) sm[t >> 6] = s;
    __syncthreads();
    if (t == 0) part[b] = sm[0] + sm[1] + sm[2] + sm[3];
}
__global__ void k_ps2(int* part, int nb) {
    if (threadIdx.x == 0) {
        int run = 0;
        for (int i = 0; i < nb; i++) { int v = part[i]; part[i] = run; run += v; }
        part[nb] = run;
    }
}
// R7: optionally emits dis[i] = rsqrt(deg_i) (deg = cnt+1) for the agg pass.
__global__ void k_ps3(const int* __restrict__ cnt, const int* __restrict__ part,
                      int* rowS, int* curs, float* dis, int N) {
    __shared__ int sm[256];
    int b = blockIdx.x, t = threadIdx.x;
    int base = b * 1024;
    int loc[4], cv[4];
    int s = 0;
#pragma unroll
    for (int j = 0; j < 4; j++) { loc[j] = s; cv[j] = cnt[base + t * 4 + j]; s += cv[j]; }
    sm[t] = s;
    __syncthreads();
    for (int o = 1; o < 256; o <<= 1) {
        int u = (t >= o) ? sm[t - o] : 0;
        __syncthreads();
        sm[t] += u;
        __syncthreads();
    }
    int incl = sm[t];
    int thrBase = part[b] + incl - s;
#pragma unroll
    for (int j = 0; j < 4; j++) {
        int idx = base + t * 4 + j;
        rowS[idx] = thrBase + loc[j];
        curs[idx] = thrBase + loc[j];
        if (dis != nullptr) dis[idx] = rsqrtf((float)(cv[j] + 1));
    }
    if (b == gridDim.x - 1 && t == 255) rowS[N] = part[b] + incl;
}

// ---------- CSR fill, XCD-range-partitioned (R6) ----------
__global__ void k_fill1(const int* __restrict__ g, const int* __restrict__ sl,
                        const int* __restrict__ dl, int* curs, int* csrS) {
    int r = blockIdx.x & 7;
    int base = (blockIdx.x >> 3) * 2048;
#pragma unroll
    for (int i = 0; i < 8; i++) {
        int e = base + i * 256 + threadIdx.x;
        int gg = g[e];
        int d = gg * NN0 + dl[e];
        if ((d >> 14) == r) {
            int pos = atomicAdd(&curs[d], 1);
            csrS[pos] = gg * NN0 + sl[e];
        }
    }
}
__global__ void k_fill2(const int2* __restrict__ edges, const int* pE,
                        int* curs, int* csrS, int shift) {
    int r = blockIdx.x & 7;
    int base = (blockIdx.x >> 3) * 2048;
    int E = *pE;
#pragma unroll
    for (int i = 0; i < 8; i++) {
        int e = base + i * 256 + threadIdx.x;
        if (e < E) {
            int2 ed = edges[e];
            if ((ed.y >> shift) == r) {
                int pos = atomicAdd(&curs[ed.y], 1);
                csrS[pos] = ed.x;
            }
        }
    }
}

// ---------- GCN aggregation + fused score ----------
// R7: agg was VALU-bound (53% busy, HBM 9%): per-edge cnt-gather+rsqrt+2 scalar
// row loads + serial csrS broadcast chain. Now: dis[] precomputed; wave batch-
// loads 64 csrS/dis entries, __shfl-broadcasts; xw rows gathered as float2/lane
// (1 dwordx2); score tanh(h.pn) fused into epilogue (k_score dispatches gone).
__global__ void k_agg(const float2* __restrict__ xw, const int* __restrict__ rowS,
                      const int* __restrict__ csrS, const float* __restrict__ dis,
                      const float* __restrict__ bias, const float* __restrict__ pn,
                      float* __restrict__ h, float* __restrict__ scores, int N) {
    int nb = gridDim.x;
    int bid = blockIdx.x;
    int sb = (bid & 7) * (nb >> 3) + (bid >> 3); // contiguous chunk per XCD
    int d = sb * 4 + (threadIdx.x >> 6);
    int lane = threadIdx.x & 63;
    int rs = rowS[d], re = rowS[d + 1];
    float a0 = 0.f, a1 = 0.f;
    for (int j0 = rs; j0 < re; j0 += 64) {
        int myj = j0 + lane;
        int sV = (myj < re) ? csrS[myj] : 0;
        float dV = (myj < re) ? dis[sV] : 0.f;
        int c64 = re - j0; if (c64 > 64) c64 = 64;
        for (int j = 0; j < c64; j++) {
            int s = __shfl(sV, j);
            float diss = __shfl(dV, j);
            float2 v = xw[s * 64 + lane];
            a0 = fmaf(diss, v.x, a0);
            a1 = fmaf(diss, v.y, a1);
        }
    }
    float disd = dis[d];
    float invd = disd * disd; // 1/deg
    float2 xd = xw[d * 64 + lane];
    float2 bv = *(const float2*)&bias[lane * 2];
    float r0 = disd * a0 + xd.x * invd + bv.x;
    float r1 = disd * a1 + xd.y * invd + bv.y;
    r0 = r0 > 0.f ? r0 : 0.f;
    r1 = r1 > 0.f ? r1 : 0.f;
    ((float2*)h)[d * 64 + lane] = make_float2(r0, r1);
    float2 pv = *(const float2*)&pn[lane * 2];
    float v = r0 * pv.x + r1 * pv.y;
    for (int o = 32; o > 0; o >>= 1) v += __shfl_down(v, o);
    if (lane == 0) scores[d] = tanhf(v);
}

// ---------- exact top-k per graph: map[old global] = new local idx or -1 ----------
__global__ void k_topk(const float* __restrict__ scores, int* __restrict__ map, int n, int k) {
    __shared__ unsigned keys[2048];
    __shared__ int sm[256];
    __shared__ int red[4];
    int b = blockIdx.x, t = threadIdx.x;
    const float* sc = scores + b * n;
    int m = n >> 8;

    for (int i = t; i < n; i += 256) keys[i] = f2o(sc[i]);
    __syncthreads();

    unsigned prefix = 0u;
    for (int bit = 31; bit >= 0; bit--) {
        unsigned trial = prefix | (1u << bit);
        int c = 0;
        for (int i = t; i < n; i += 256) c += (keys[i] >= trial) ? 1 : 0;
        for (int o = 32; o > 0; o >>= 1) c += __shfl_down(c, o);
        if ((t & 63) == 0) red[t >> 6] = c;
        __syncthreads();
        int tot = red[0] + red[1] + red[2] + red[3];
        __syncthreads();
        if (tot >= k) prefix = trial;
    }
    unsigned T = prefix;

    int c = 0;
    for (int i = t; i < n; i += 256) c += (keys[i] > T) ? 1 : 0;
    for (int o = 32; o > 0; o >>= 1) c += __shfl_down(c, o);
    if ((t & 63) == 0) red[t >> 6] = c;
    __syncthreads();
    int mEq = k - (red[0] + red[1] + red[2] + red[3]);
    __syncthreads();

    int base = t * m;
    int eqc = 0;
    for (int j = 0; j < m; j++) eqc += (keys[base + j] == T) ? 1 : 0;
    sm[t] = eqc;
    __syncthreads();
    for (int o = 1; o < 256; o <<= 1) {
        int u = (t >= o) ? sm[t - o] : 0;
        __syncthreads();
        sm[t] += u;
        __syncthreads();
    }
    int er = sm[t] - eqc;
    __syncthreads();

    unsigned kb = 0; int kc = 0;
    for (int j = 0; j < m; j++) {
        unsigned ky = keys[base + j];
        bool kp = (ky > T) || (ky == T && er < mEq);
        if (ky == T) er++;
        if (kp) { kb |= (1u << j); kc++; }
    }
    sm[t] = kc;
    __syncthreads();
    for (int o = 1; o < 256; o <<= 1) {
        int u = (t >= o) ? sm[t - o] : 0;
        __syncthreads();
        sm[t] += u;
        __syncthreads();
    }
    int nidx = sm[t] - kc;
    for (int j = 0; j < m; j++) {
        map[b * n + base + j] = ((kb >> j) & 1u) ? nidx++ : -1;
    }
}

// ---------- compact kept nodes: xn[g*k+new] = h[old] * score[old] ----------
__global__ void k_compact(const float* __restrict__ h, const float* __restrict__ scores,
                          const int* __restrict__ map, float* __restrict__ xn,
                          int N, int n, int k) {
    int wid = (blockIdx.x * 256 + threadIdx.x) >> 6;
    int lane = threadIdx.x & 63;
    int mi = map[wid];
    if (mi < 0) return;
    float s = scores[wid];
    int gg = wid / n;
    int dst = (gg * k + mi) * CF;
    xn[dst + lane]      = h[wid * CF + lane] * s;
    xn[dst + 64 + lane] = h[wid * CF + 64 + lane] * s;
}

// ---------- edge remap + compaction, atomic-free two-pass (R6) ----------
__global__ void k_remapA1(const int* __restrict__ g, const int* __restrict__ sl,
                          const int* __restrict__ dl, const int* __restrict__ map,
                          int* __restrict__ wcnt) {
    int e = blockIdx.x * 256 + threadIdx.x;
    int gg = g[e];
    bool valid = (map[gg * NN0 + sl[e]] >= 0) && (map[gg * NN0 + dl[e]] >= 0);
    unsigned long long mask = __ballot(valid);
    if ((threadIdx.x & 63) == 0) wcnt[e >> 6] = __popcll(mask);
}
__global__ void k_remapB1(const int* __restrict__ g, const int* __restrict__ sl,
                          const int* __restrict__ dl, const int* __restrict__ map,
                          const int* __restrict__ wbase, int2* __restrict__ eout,
                          int* __restrict__ pTot, int k) {
    int e = blockIdx.x * 256 + threadIdx.x;
    int lane = threadIdx.x & 63;
    int gg = g[e];
    int ns = map[gg * NN0 + sl[e]];
    int nd = map[gg * NN0 + dl[e]];
    bool valid = (ns >= 0 && nd >= 0);
    unsigned long long mask = __ballot(valid);
    if (valid) {
        int off = __popcll(mask & ((1ull << lane) - 1ull));
        eout[wbase[e >> 6] + off] = make_int2(gg * k + ns, gg * k + nd);
    }
    if (e == 0) pTot[0] = wbase[ET >> 6];
}
__global__ void k_remapA2(const int2* __restrict__ ein, const int* pE,
                          const int* __restrict__ map, int* __restrict__ wcnt) {
    int e = blockIdx.x * 256 + threadIdx.x;
    bool valid = false;
    if (e < *pE) {
        int2 ed = ein[e];
        valid = (map[ed.x] >= 0) && (map[ed.y] >= 0);
    }
    unsigned long long mask = __ballot(valid);
    if ((threadIdx.x & 63) == 0) wcnt[e >> 6] = __popcll(mask);
}
__global__ void k_remapB2(const int2* __restrict__ ein, const int* pE,
                          const int* __restrict__ map, const int* __restrict__ wbase,
                          int2* __restrict__ eout, int* __restrict__ pTot,
                          int n, int k) {
    int e = blockIdx.x * 256 + threadIdx.x;
    int lane = threadIdx.x & 63;
    bool valid = false;
    int gg = 0, ns = 0, nd = 0;
    if (e < *pE) {
        int2 ed = ein[e];
        ns = map[ed.x]; nd = map[ed.y];
        gg = ed.x / n;
        valid = (ns >= 0 && nd >= 0);
    }
    unsigned long long mask = __ballot(valid);
    if (valid) {
        int off = __popcll(mask & ((1ull << lane) - 1ull));
        eout[wbase[e >> 6] + off] = make_int2(gg * k + ns, gg * k + nd);
    }
    if (e == 0) pTot[0] = wbase[ET >> 6];
}

// ---------- fused layer-3 pool ----------
__global__ void k_pool3(const float* __restrict__ h, const float* __restrict__ scores,
                        const int* __restrict__ map, float* __restrict__ pooled) {
    int b = blockIdx.x, cthr = threadIdx.x; // 128 threads
    float acc = 0.f;
    for (int i = 0; i < 512; i++) {
        int gi = b * 512 + i;
        int mi = map[gi];
        if (mi >= 0) acc += h[gi * CF + cthr] * scores[gi];
    }
    pooled[b * CF + cthr] = acc;
}

// ---------- final MLP ----------
__global__ void k_mlp(const float* __restrict__ pooled, const float* __restrict__ Wm,
                      const float* __restrict__ bm, float* __restrict__ out) {
    int b = blockIdx.x, t = threadIdx.x;
    if (t < OUTF) {
        float acc = bm[t];
        for (int c2 = 0; c2 < CF; c2++) acc += pooled[b * CF + c2] * Wm[c2 * OUTF + t];
        out[b * OUTF + t] = acc;
    }
}

extern "C" void kernel_launch(void* const* d_in, const int* in_sizes, int n_in,
                              void* d_out, int out_size, void* d_ws, size_t ws_size,
                              hipStream_t stream) {
    const float* x  = (const float*)d_in[0];
    const int* sl   = (const int*)d_in[1];
    const int* dl   = (const int*)d_in[2];
    const int* g    = (const int*)d_in[3];
    const float* W1 = (const float*)d_in[4];
    const float* b1 = (const float*)d_in[5];
    const float* p1 = (const float*)d_in[6];
    const float* W2 = (const float*)d_in[7];
    const float* b2 = (const float*)d_in[8];
    const float* p2 = (const float*)d_in[9];
    const float* W3 = (const float*)d_in[10];
    const float* b3 = (const float*)d_in[11];
    const float* p3 = (const float*)d_in[12];
    const float* Wm = (const float*)d_in[13];
    const float* bm = (const float*)d_in[14];

    // workspace layout (~145.8 MB total)
    char* ws = (char*)d_ws;
    float* A    = (float*)(ws + 0);            // 64MB
    float* Bb   = (float*)(ws + 67108864ull);  // 64MB
    int*   csrS = (int*)  (ws + 134217728ull); // 8MB
    int*   cnt  = (int*)  (ws + 142606336ull); // 512KB
    int*   rowS = (int*)  (ws + 143130624ull); // 512KB+4
    int*   curs = (int*)  (ws + 143655168ull); // 512KB
    float* scor = (float*)(ws + 144179456ull); // 512KB
    int*   map  = (int*)  (ws + 144703744ull); // 512KB
    float* pn   = (float*)(ws + 145228032ull); // 1.5KB
    float* pool = (float*)(ws + 145230080ull); // 32KB
    int*   ecnt = (int*)  (ws + 145262848ull); // counters
    int*   part = (int*)  (ws + 145263104ull); // scan partials (<=129 ints)
    float* dis  = (float*)(ws + 145264640ull); // 512KB: per-node rsqrt(deg)

    // aliased regions (lifetimes verified):
    int2*  EA  = (int2*)(ws + 33554432ull);              // A[32:48MB]
    int2*  EB  = (int2*)(ws + 67108864ull);              // Bb[0:16MB]
    float* x2  = A;                                      // A[0:32MB]
    float* xw2 = Bb;                                     // Bb[0:32MB]
    float* h2  = A;                                      // A[0:32MB]
    float* x3  = (float*)(ws + 100663296ull);            // Bb[32:48MB]
    float* xw3 = A;                                      // A[0:16MB]
    float* h3  = Bb;                                     // Bb[0:16MB]
    int*   wcnt  = (int*)(ws + 50331648ull);             // A[48:64MB] region
    int*   wbase = (int*)(ws + 50462720ull);

    k_normp<<<3, 128, 0, stream>>>(p1, p2, p3, pn);

    // ================= layer 1 (N=131072, n=2048, k=1024) =================
    k_gemm<<<512, 256, 0, stream>>>(x, W1, A, 131072);
    hipMemsetAsync(cnt, 0, 524288, stream);
    k_hist1<<<8192, 256, 0, stream>>>(g, dl, cnt);
    k_ps1<<<128, 256, 0, stream>>>(cnt, part);
    k_ps2<<<1, 64, 0, stream>>>(part, 128);
    k_ps3<<<128, 256, 0, stream>>>(cnt, part, rowS, curs, dis, 131072);
    k_fill1<<<8192, 256, 0, stream>>>(g, sl, dl, curs, csrS);
    k_agg<<<32768, 256, 0, stream>>>((const float2*)A, rowS, csrS, dis, b1, pn, Bb, scor, 131072);
    k_topk<<<64, 256, 0, stream>>>(scor, map, 2048, 1024);
    k_compact<<<32768, 256, 0, stream>>>(Bb, scor, map, x2, 131072, 2048, 1024);
    k_remapA1<<<8192, 256, 0, stream>>>(g, sl, dl, map, wcnt);
    k_ps1<<<32, 256, 0, stream>>>(wcnt, part);
    k_ps2<<<1, 64, 0, stream>>>(part, 32);
    k_ps3<<<32, 256, 0, stream>>>(wcnt, part, wbase, wbase, nullptr, 32768);
    k_remapB1<<<8192, 256, 0, stream>>>(g, sl, dl, map, wbase, EA, &ecnt[0], 1024);

    // ================= layer 2 (N=65536, n=1024, k=512) =================
    k_gemm<<<256, 256, 0, stream>>>(x2, W2, xw2, 65536);
    hipMemsetAsync(cnt, 0, 262144, stream);
    k_hist2<<<8192, 256, 0, stream>>>(EA, &ecnt[0], cnt);
    k_ps1<<<64, 256, 0, stream>>>(cnt, part);
    k_ps2<<<1, 64, 0, stream>>>(part, 64);
    k_ps3<<<64, 256, 0, stream>>>(cnt, part, rowS, curs, dis, 65536);
    k_fill2<<<8192, 256, 0, stream>>>(EA, &ecnt[0], curs, csrS, 13);
    k_agg<<<16384, 256, 0, stream>>>((const float2*)xw2, rowS, csrS, dis, b2, pn + 128, h2, scor, 65536);
    k_topk<<<64, 256, 0, stream>>>(scor, map, 1024, 512);
    k_compact<<<16384, 256, 0, stream>>>(h2, scor, map, x3, 65536, 1024, 512);
    k_remapA2<<<8192, 256, 0, stream>>>(EA, &ecnt[0], map, wcnt);
    k_ps1<<<32, 256, 0, stream>>>(wcnt, part);
    k_ps2<<<1, 64, 0, stream>>>(part, 32);
    k_ps3<<<32, 256, 0, stream>>>(wcnt, part, wbase, wbase, nullptr, 32768);
    k_remapB2<<<8192, 256, 0, stream>>>(EA, &ecnt[0], map, wbase, EB, &ecnt[1], 1024, 512);

    // ================= layer 3 (N=32768, n=512, k=256) =================
    k_gemm<<<128, 256, 0, stream>>>(x3, W3, xw3, 32768);
    hipMemsetAsync(cnt, 0, 131072, stream);
    k_hist2<<<8192, 256, 0, stream>>>(EB, &ecnt[1], cnt);
    k_ps1<<<32, 256, 0, stream>>>(cnt, part);
    k_ps2<<<1, 64, 0, stream>>>(part, 32);
    k_ps3<<<32, 256, 0, stream>>>(cnt, part, rowS, curs, dis, 32768);
    k_fill2<<<8192, 256, 0, stream>>>(EB, &ecnt[1], curs, csrS, 12);
    k_agg<<<8192, 256, 0, stream>>>((const float2*)xw3, rowS, csrS, dis, b3, pn + 256, h3, scor, 32768);
    k_topk<<<64, 256, 0, stream>>>(scor, map, 512, 256);
    k_pool3<<<64, 128, 0, stream>>>(h3, scor, map, pool);
    k_mlp<<<64, 64, 0, stream>>>(pool, Wm, bm, (float*)d_out);
}

// Round 10
// 834.969 us; speedup vs baseline: 1.6646x; 1.0486x over previous
//
#include <hip/hip_runtime.h>
#include <math.h>

#define BQ   64
#define NN0  2048
#define CF   128
#define ET   2097152
#define OUTF 16

// ---------- helpers ----------
static __device__ __forceinline__ unsigned f2o(float f) {
    unsigned u = __float_as_uint(f);
    return (u & 0x80000000u) ? ~u : (u | 0x80000000u);
}

// ---------- normalize p vectors ----------
__global__ void k_normp(const float* p1, const float* p2, const float* p3, float* pn) {
    const float* ps[3] = {p1, p2, p3};
    const float* p = ps[blockIdx.x];
    int t = threadIdx.x; // 128 threads
    float v = p[t];
    float s = v * v;
    for (int o = 32; o > 0; o >>= 1) s += __shfl_down(s, o);
    __shared__ float ws2[2];
    if ((t & 63) == 0) ws2[t >> 6] = s;
    __syncthreads();
    float tot = ws2[0] + ws2[1];
    pn[blockIdx.x * CF + t] = v / sqrtf(tot);
}

// ---------- GEMM: Y[N][128] = X[N][128] @ W[128][128], f32 ----------
__global__ __launch_bounds__(256, 2) void k_gemm(const float* __restrict__ X,
                                                 const float* __restrict__ W,
                                                 float* __restrict__ Y, int N) {
    __shared__ float xT[32][260];
    __shared__ float Wc[32][128];
    int t = threadIdx.x;
    int cg = t & 15, rg = t >> 4;
    int c0 = cg * 8, r0 = rg * 16;
    int rowBase = blockIdx.x * 256;

    float acc[16][8];
#pragma unroll
    for (int i = 0; i < 16; i++)
#pragma unroll
        for (int j = 0; j < 8; j++) acc[i][j] = 0.f;

    for (int kc = 0; kc < 4; kc++) {
        __syncthreads();
#pragma unroll
        for (int j = 0; j < 8; j++) {
            int id = t + 256 * j;
            int r = id >> 3;
            int k4 = id & 7;
            float4 v = *(const float4*)&X[(rowBase + r) * CF + kc * 32 + k4 * 4];
            int kk = k4 * 4;
            xT[kk + 0][r] = v.x; xT[kk + 1][r] = v.y;
            xT[kk + 2][r] = v.z; xT[kk + 3][r] = v.w;
        }
#pragma unroll
        for (int j = 0; j < 4; j++) {
            int id = t + 256 * j;
            int kk = id >> 5;
            int cc = (id & 31) * 4;
            *(float4*)&Wc[kk][cc] = *(const float4*)&W[(kc * 32 + kk) * CF + cc];
        }
        __syncthreads();
#pragma unroll 4
        for (int kk = 0; kk < 32; kk++) {
            float xr[16];
#pragma unroll
            for (int i = 0; i < 16; i += 4)
                *(float4*)&xr[i] = *(float4*)&xT[kk][r0 + i];
            float wv[8];
            *(float4*)&wv[0] = *(float4*)&Wc[kk][c0];
            *(float4*)&wv[4] = *(float4*)&Wc[kk][c0 + 4];
#pragma unroll
            for (int i = 0; i < 16; i++)
#pragma unroll
                for (int j = 0; j < 8; j++)
                    acc[i][j] = fmaf(xr[i], wv[j], acc[i][j]);
        }
    }
#pragma unroll
    for (int i = 0; i < 16; i++) {
        int r = rowBase + r0 + i;
        *(float4*)&Y[r * CF + c0]     = make_float4(acc[i][0], acc[i][1], acc[i][2], acc[i][3]);
        *(float4*)&Y[r * CF + c0 + 4] = make_float4(acc[i][4], acc[i][5], acc[i][6], acc[i][7]);
    }
}

// ---------- histograms ----------
__global__ void k_hist1(const int* __restrict__ g, const int* __restrict__ dl, int* cnt) {
    int e = blockIdx.x * 256 + threadIdx.x;
    if (e < ET) atomicAdd(&cnt[g[e] * NN0 + dl[e]], 1);
}
__global__ void k_hist2(const int2* __restrict__ edges, const int* pE, int* cnt) {
    int e = blockIdx.x * 256 + threadIdx.x;
    if (e < *pE) atomicAdd(&cnt[edges[e].y], 1);
}

// ---------- exclusive scan (3 kernels), chunk=1024 ----------
__global__ void k_ps1(const int* __restrict__ cnt, int* part) {
    int b = blockIdx.x, t = threadIdx.x;
    int base = b * 1024;
    int s = 0;
    for (int j = t; j < 1024; j += 256) s += cnt[base + j];
    for (int o = 32; o > 0; o >>= 1) s += __shfl_down(s, o);
    __shared__ int sm[4];
    if ((t & 63) == 0) sm[t >> 6] = s;
    __syncthreads();
    if (t == 0) part[b] = sm[0] + sm[1] + sm[2] + sm[3];
}
__global__ void k_ps2(int* part, int nb) {
    if (threadIdx.x == 0) {
        int run = 0;
        for (int i = 0; i < nb; i++) { int v = part[i]; part[i] = run; run += v; }
        part[nb] = run;
    }
}
// emits dis[i] = rsqrt(deg_i) (deg = cnt+1) for the agg pass.
__global__ void k_ps3(const int* __restrict__ cnt, const int* __restrict__ part,
                      int* rowS, int* curs, float* dis, int N) {
    __shared__ int sm[256];
    int b = blockIdx.x, t = threadIdx.x;
    int base = b * 1024;
    int loc[4], cv[4];
    int s = 0;
#pragma unroll
    for (int j = 0; j < 4; j++) { loc[j] = s; cv[j] = cnt[base + t * 4 + j]; s += cv[j]; }
    sm[t] = s;
    __syncthreads();
    for (int o = 1; o < 256; o <<= 1) {
        int u = (t >= o) ? sm[t - o] : 0;
        __syncthreads();
        sm[t] += u;
        __syncthreads();
    }
    int incl = sm[t];
    int thrBase = part[b] + incl - s;
#pragma unroll
    for (int j = 0; j < 4; j++) {
        int idx = base + t * 4 + j;
        rowS[idx] = thrBase + loc[j];
        curs[idx] = thrBase + loc[j];
        if (dis != nullptr) dis[idx] = rsqrtf((float)(cv[j] + 1));
    }
    if (b == gridDim.x - 1 && t == 255) rowS[N] = part[b] + incl;
}

// ---------- CSR fill, XCD-range-partitioned (R6) ----------
__global__ void k_fill1(const int* __restrict__ g, const int* __restrict__ sl,
                        const int* __restrict__ dl, int* curs, int* csrS) {
    int r = blockIdx.x & 7;
    int base = (blockIdx.x >> 3) * 2048;
#pragma unroll
    for (int i = 0; i < 8; i++) {
        int e = base + i * 256 + threadIdx.x;
        int gg = g[e];
        int d = gg * NN0 + dl[e];
        if ((d >> 14) == r) {
            int pos = atomicAdd(&curs[d], 1);
            csrS[pos] = gg * NN0 + sl[e];
        }
    }
}
__global__ void k_fill2(const int2* __restrict__ edges, const int* pE,
                        int* curs, int* csrS, int shift) {
    int r = blockIdx.x & 7;
    int base = (blockIdx.x >> 3) * 2048;
    int E = *pE;
#pragma unroll
    for (int i = 0; i < 8; i++) {
        int e = base + i * 256 + threadIdx.x;
        if (e < E) {
            int2 ed = edges[e];
            if ((ed.y >> shift) == r) {
                int pos = atomicAdd(&curs[ed.y], 1);
                csrS[pos] = ed.x;
            }
        }
    }
}

// ---------- GCN aggregation + fused score ----------
// R8 post-mortem: after instruction trim, agg is gather-LATENCY-bound (VALU 35%,
// HBM 11%, 1GB of L2/L3 row gathers, 1 load in flight per wave). R9: 4-deep
// software pipeline - 4 independent row gathers issued back-to-back per step
// (compiler staggers vmcnt waits), 4x memory-level parallelism per wave.
__global__ void k_agg(const float2* __restrict__ xw, const int* __restrict__ rowS,
                      const int* __restrict__ csrS, const float* __restrict__ dis,
                      const float* __restrict__ bias, const float* __restrict__ pn,
                      float* __restrict__ h, float* __restrict__ scores, int N) {
    int nb = gridDim.x;
    int bid = blockIdx.x;
    int sb = (bid & 7) * (nb >> 3) + (bid >> 3); // contiguous chunk per XCD
    int d = sb * 4 + (threadIdx.x >> 6);
    int lane = threadIdx.x & 63;
    int rs = rowS[d], re = rowS[d + 1];
    float a0 = 0.f, a1 = 0.f;
    for (int j0 = rs; j0 < re; j0 += 64) {
        int myj = j0 + lane;
        int sV = (myj < re) ? csrS[myj] : 0;
        float dV = (myj < re) ? dis[sV] : 0.f;
        int c64 = re - j0; if (c64 > 64) c64 = 64;
        int j = 0;
        for (; j + 4 <= c64; j += 4) {
            int s0 = __shfl(sV, j),     s1 = __shfl(sV, j + 1);
            int s2 = __shfl(sV, j + 2), s3 = __shfl(sV, j + 3);
            float d0 = __shfl(dV, j),     d1 = __shfl(dV, j + 1);
            float d2 = __shfl(dV, j + 2), d3 = __shfl(dV, j + 3);
            float2 v0 = xw[s0 * 64 + lane];
            float2 v1 = xw[s1 * 64 + lane];
            float2 v2 = xw[s2 * 64 + lane];
            float2 v3 = xw[s3 * 64 + lane];
            a0 = fmaf(d0, v0.x, a0); a1 = fmaf(d0, v0.y, a1);
            a0 = fmaf(d1, v1.x, a0); a1 = fmaf(d1, v1.y, a1);
            a0 = fmaf(d2, v2.x, a0); a1 = fmaf(d2, v2.y, a1);
            a0 = fmaf(d3, v3.x, a0); a1 = fmaf(d3, v3.y, a1);
        }
        for (; j < c64; j++) {
            int s = __shfl(sV, j);
            float diss = __shfl(dV, j);
            float2 v = xw[s * 64 + lane];
            a0 = fmaf(diss, v.x, a0);
            a1 = fmaf(diss, v.y, a1);
        }
    }
    float disd = dis[d];
    float invd = disd * disd; // 1/deg
    float2 xd = xw[d * 64 + lane];
    float2 bv = *(const float2*)&bias[lane * 2];
    float r0 = disd * a0 + xd.x * invd + bv.x;
    float r1 = disd * a1 + xd.y * invd + bv.y;
    r0 = r0 > 0.f ? r0 : 0.f;
    r1 = r1 > 0.f ? r1 : 0.f;
    ((float2*)h)[d * 64 + lane] = make_float2(r0, r1);
    float2 pv = *(const float2*)&pn[lane * 2];
    float v = r0 * pv.x + r1 * pv.y;
    for (int o = 32; o > 0; o >>= 1) v += __shfl_down(v, o);
    if (lane == 0) scores[d] = tanhf(v);
}

// ---------- exact top-k per graph: map[old global] = new local idx or -1 ----------
__global__ void k_topk(const float* __restrict__ scores, int* __restrict__ map, int n, int k) {
    __shared__ unsigned keys[2048];
    __shared__ int sm[256];
    __shared__ int red[4];
    int b = blockIdx.x, t = threadIdx.x;
    const float* sc = scores + b * n;
    int m = n >> 8;

    for (int i = t; i < n; i += 256) keys[i] = f2o(sc[i]);
    __syncthreads();

    unsigned prefix = 0u;
    for (int bit = 31; bit >= 0; bit--) {
        unsigned trial = prefix | (1u << bit);
        int c = 0;
        for (int i = t; i < n; i += 256) c += (keys[i] >= trial) ? 1 : 0;
        for (int o = 32; o > 0; o >>= 1) c += __shfl_down(c, o);
        if ((t & 63) == 0) red[t >> 6] = c;
        __syncthreads();
        int tot = red[0] + red[1] + red[2] + red[3];
        __syncthreads();
        if (tot >= k) prefix = trial;
    }
    unsigned T = prefix;

    int c = 0;
    for (int i = t; i < n; i += 256) c += (keys[i] > T) ? 1 : 0;
    for (int o = 32; o > 0; o >>= 1) c += __shfl_down(c, o);
    if ((t & 63) == 0) red[t >> 6] = c;
    __syncthreads();
    int mEq = k - (red[0] + red[1] + red[2] + red[3]);
    __syncthreads();

    int base = t * m;
    int eqc = 0;
    for (int j = 0; j < m; j++) eqc += (keys[base + j] == T) ? 1 : 0;
    sm[t] = eqc;
    __syncthreads();
    for (int o = 1; o < 256; o <<= 1) {
        int u = (t >= o) ? sm[t - o] : 0;
        __syncthreads();
        sm[t] += u;
        __syncthreads();
    }
    int er = sm[t] - eqc;
    __syncthreads();

    unsigned kb = 0; int kc = 0;
    for (int j = 0; j < m; j++) {
        unsigned ky = keys[base + j];
        bool kp = (ky > T) || (ky == T && er < mEq);
        if (ky == T) er++;
        if (kp) { kb |= (1u << j); kc++; }
    }
    sm[t] = kc;
    __syncthreads();
    for (int o = 1; o < 256; o <<= 1) {
        int u = (t >= o) ? sm[t - o] : 0;
        __syncthreads();
        sm[t] += u;
        __syncthreads();
    }
    int nidx = sm[t] - kc;
    for (int j = 0; j < m; j++) {
        map[b * n + base + j] = ((kb >> j) & 1u) ? nidx++ : -1;
    }
}

// ---------- compact kept nodes: xn[g*k+new] = h[old] * score[old] ----------
__global__ void k_compact(const float* __restrict__ h, const float* __restrict__ scores,
                          const int* __restrict__ map, float* __restrict__ xn,
                          int N, int n, int k) {
    int wid = (blockIdx.x * 256 + threadIdx.x) >> 6;
    int lane = threadIdx.x & 63;
    int mi = map[wid];
    if (mi < 0) return;
    float s = scores[wid];
    int gg = wid / n;
    int dst = (gg * k + mi) * CF;
    xn[dst + lane]      = h[wid * CF + lane] * s;
    xn[dst + 64 + lane] = h[wid * CF + 64 + lane] * s;
}

// ---------- edge remap + compaction, atomic-free two-pass (R6) ----------
__global__ void k_remapA1(const int* __restrict__ g, const int* __restrict__ sl,
                          const int* __restrict__ dl, const int* __restrict__ map,
                          int* __restrict__ wcnt) {
    int e = blockIdx.x * 256 + threadIdx.x;
    int gg = g[e];
    bool valid = (map[gg * NN0 + sl[e]] >= 0) && (map[gg * NN0 + dl[e]] >= 0);
    unsigned long long mask = __ballot(valid);
    if ((threadIdx.x & 63) == 0) wcnt[e >> 6] = __popcll(mask);
}
__global__ void k_remapB1(const int* __restrict__ g, const int* __restrict__ sl,
                          const int* __restrict__ dl, const int* __restrict__ map,
                          const int* __restrict__ wbase, int2* __restrict__ eout,
                          int* __restrict__ pTot, int k) {
    int e = blockIdx.x * 256 + threadIdx.x;
    int lane = threadIdx.x & 63;
    int gg = g[e];
    int ns = map[gg * NN0 + sl[e]];
    int nd = map[gg * NN0 + dl[e]];
    bool valid = (ns >= 0 && nd >= 0);
    unsigned long long mask = __ballot(valid);
    if (valid) {
        int off = __popcll(mask & ((1ull << lane) - 1ull));
        eout[wbase[e >> 6] + off] = make_int2(gg * k + ns, gg * k + nd);
    }
    if (e == 0) pTot[0] = wbase[ET >> 6];
}
__global__ void k_remapA2(const int2* __restrict__ ein, const int* pE,
                          const int* __restrict__ map, int* __restrict__ wcnt) {
    int e = blockIdx.x * 256 + threadIdx.x;
    bool valid = false;
    if (e < *pE) {
        int2 ed = ein[e];
        valid = (map[ed.x] >= 0) && (map[ed.y] >= 0);
    }
    unsigned long long mask = __ballot(valid);
    if ((threadIdx.x & 63) == 0) wcnt[e >> 6] = __popcll(mask);
}
__global__ void k_remapB2(const int2* __restrict__ ein, const int* pE,
                          const int* __restrict__ map, const int* __restrict__ wbase,
                          int2* __restrict__ eout, int* __restrict__ pTot,
                          int n, int k) {
    int e = blockIdx.x * 256 + threadIdx.x;
    int lane = threadIdx.x & 63;
    bool valid = false;
    int gg = 0, ns = 0, nd = 0;
    if (e < *pE) {
        int2 ed = ein[e];
        ns = map[ed.x]; nd = map[ed.y];
        gg = ed.x / n;
        valid = (ns >= 0 && nd >= 0);
    }
    unsigned long long mask = __ballot(valid);
    if (valid) {
        int off = __popcll(mask & ((1ull << lane) - 1ull));
        eout[wbase[e >> 6] + off] = make_int2(gg * k + ns, gg * k + nd);
    }
    if (e == 0) pTot[0] = wbase[ET >> 6];
}

// ---------- fused layer-3 pool ----------
__global__ void k_pool3(const float* __restrict__ h, const float* __restrict__ scores,
                        const int* __restrict__ map, float* __restrict__ pooled) {
    int b = blockIdx.x, cthr = threadIdx.x; // 128 threads
    float acc = 0.f;
    for (int i = 0; i < 512; i++) {
        int gi = b * 512 + i;
        int mi = map[gi];
        if (mi >= 0) acc += h[gi * CF + cthr] * scores[gi];
    }
    pooled[b * CF + cthr] = acc;
}

// ---------- final MLP ----------
__global__ void k_mlp(const float* __restrict__ pooled, const float* __restrict__ Wm,
                      const float* __restrict__ bm, float* __restrict__ out) {
    int b = blockIdx.x, t = threadIdx.x;
    if (t < OUTF) {
        float acc = bm[t];
        for (int c2 = 0; c2 < CF; c2++) acc += pooled[b * CF + c2] * Wm[c2 * OUTF + t];
        out[b * OUTF + t] = acc;
    }
}

extern "C" void kernel_launch(void* const* d_in, const int* in_sizes, int n_in,
                              void* d_out, int out_size, void* d_ws, size_t ws_size,
                              hipStream_t stream) {
    const float* x  = (const float*)d_in[0];
    const int* sl   = (const int*)d_in[1];
    const int* dl   = (const int*)d_in[2];
    const int* g    = (const int*)d_in[3];
    const float* W1 = (const float*)d_in[4];
    const float* b1 = (const float*)d_in[5];
    const float* p1 = (const float*)d_in[6];
    const float* W2 = (const float*)d_in[7];
    const float* b2 = (const float*)d_in[8];
    const float* p2 = (const float*)d_in[9];
    const float* W3 = (const float*)d_in[10];
    const float* b3 = (const float*)d_in[11];
    const float* p3 = (const float*)d_in[12];
    const float* Wm = (const float*)d_in[13];
    const float* bm = (const float*)d_in[14];

    // workspace layout (~145.8 MB total)
    char* ws = (char*)d_ws;
    float* A    = (float*)(ws + 0);            // 64MB
    float* Bb   = (float*)(ws + 67108864ull);  // 64MB
    int*   csrS = (int*)  (ws + 134217728ull); // 8MB
    int*   cnt  = (int*)  (ws + 142606336ull); // 512KB
    int*   rowS = (int*)  (ws + 143130624ull); // 512KB+4
    int*   curs = (int*)  (ws + 143655168ull); // 512KB
    float* scor = (float*)(ws + 144179456ull); // 512KB
    int*   map  = (int*)  (ws + 144703744ull); // 512KB
    float* pn   = (float*)(ws + 145228032ull); // 1.5KB
    float* pool = (float*)(ws + 145230080ull); // 32KB
    int*   ecnt = (int*)  (ws + 145262848ull); // counters
    int*   part = (int*)  (ws + 145263104ull); // scan partials (<=129 ints)
    float* dis  = (float*)(ws + 145264640ull); // 512KB: per-node rsqrt(deg)

    // aliased regions (lifetimes verified):
    int2*  EA  = (int2*)(ws + 33554432ull);              // A[32:48MB]
    int2*  EB  = (int2*)(ws + 67108864ull);              // Bb[0:16MB]
    float* x2  = A;                                      // A[0:32MB]
    float* xw2 = Bb;                                     // Bb[0:32MB]
    float* h2  = A;                                      // A[0:32MB]
    float* x3  = (float*)(ws + 100663296ull);            // Bb[32:48MB]
    float* xw3 = A;                                      // A[0:16MB]
    float* h3  = Bb;                                     // Bb[0:16MB]
    int*   wcnt  = (int*)(ws + 50331648ull);             // A[48:64MB] region
    int*   wbase = (int*)(ws + 50462720ull);

    k_normp<<<3, 128, 0, stream>>>(p1, p2, p3, pn);

    // ================= layer 1 (N=131072, n=2048, k=1024) =================
    k_gemm<<<512, 256, 0, stream>>>(x, W1, A, 131072);
    hipMemsetAsync(cnt, 0, 524288, stream);
    k_hist1<<<8192, 256, 0, stream>>>(g, dl, cnt);
    k_ps1<<<128, 256, 0, stream>>>(cnt, part);
    k_ps2<<<1, 64, 0, stream>>>(part, 128);
    k_ps3<<<128, 256, 0, stream>>>(cnt, part, rowS, curs, dis, 131072);
    k_fill1<<<8192, 256, 0, stream>>>(g, sl, dl, curs, csrS);
    k_agg<<<32768, 256, 0, stream>>>((const float2*)A, rowS, csrS, dis, b1, pn, Bb, scor, 131072);
    k_topk<<<64, 256, 0, stream>>>(scor, map, 2048, 1024);
    k_compact<<<32768, 256, 0, stream>>>(Bb, scor, map, x2, 131072, 2048, 1024);
    k_remapA1<<<8192, 256, 0, stream>>>(g, sl, dl, map, wcnt);
    k_ps1<<<32, 256, 0, stream>>>(wcnt, part);
    k_ps2<<<1, 64, 0, stream>>>(part, 32);
    k_ps3<<<32, 256, 0, stream>>>(wcnt, part, wbase, wbase, nullptr, 32768);
    k_remapB1<<<8192, 256, 0, stream>>>(g, sl, dl, map, wbase, EA, &ecnt[0], 1024);

    // ================= layer 2 (N=65536, n=1024, k=512) =================
    k_gemm<<<256, 256, 0, stream>>>(x2, W2, xw2, 65536);
    hipMemsetAsync(cnt, 0, 262144, stream);
    k_hist2<<<8192, 256, 0, stream>>>(EA, &ecnt[0], cnt);
    k_ps1<<<64, 256, 0, stream>>>(cnt, part);
    k_ps2<<<1, 64, 0, stream>>>(part, 64);
    k_ps3<<<64, 256, 0, stream>>>(cnt, part, rowS, curs, dis, 65536);
    k_fill2<<<8192, 256, 0, stream>>>(EA, &ecnt[0], curs, csrS, 13);
    k_agg<<<16384, 256, 0, stream>>>((const float2*)xw2, rowS, csrS, dis, b2, pn + 128, h2, scor, 65536);
    k_topk<<<64, 256, 0, stream>>>(scor, map, 1024, 512);
    k_compact<<<16384, 256, 0, stream>>>(h2, scor, map, x3, 65536, 1024, 512);
    k_remapA2<<<8192, 256, 0, stream>>>(EA, &ecnt[0], map, wcnt);
    k_ps1<<<32, 256, 0, stream>>>(wcnt, part);
    k_ps2<<<1, 64, 0, stream>>>(part, 32);
    k_ps3<<<32, 256, 0, stream>>>(wcnt, part, wbase, wbase, nullptr, 32768);
    k_remapB2<<<8192, 256, 0, stream>>>(EA, &ecnt[0], map, wbase, EB, &ecnt[1], 1024, 512);

    // ================= layer 3 (N=32768, n=512, k=256) =================
    k_gemm<<<128, 256, 0, stream>>>(x3, W3, xw3, 32768);
    hipMemsetAsync(cnt, 0, 131072, stream);
    k_hist2<<<8192, 256, 0, stream>>>(EB, &ecnt[1], cnt);
    k_ps1<<<32, 256, 0, stream>>>(cnt, part);
    k_ps2<<<1, 64, 0, stream>>>(part, 32);
    k_ps3<<<32, 256, 0, stream>>>(cnt, part, rowS, curs, dis, 32768);
    k_fill2<<<8192, 256, 0, stream>>>(EB, &ecnt[1], curs, csrS, 12);
    k_agg<<<8192, 256, 0, stream>>>((const float2*)xw3, rowS, csrS, dis, b3, pn + 256, h3, scor, 32768);
    k_topk<<<64, 256, 0, stream>>>(scor, map, 512, 256);
    k_pool3<<<64, 128, 0, stream>>>(h3, scor, map, pool);
    k_mlp<<<64, 64, 0, stream>>>(pool, Wm, bm, (float*)d_out);
}

// Round 11
// 805.906 us; speedup vs baseline: 1.7247x; 1.0361x over previous
//
#include <hip/hip_runtime.h>
#include <math.h>

#define BQ   64
#define NN0  2048
#define CF   128
#define ET   2097152
#define OUTF 16

// ---------- helpers ----------
static __device__ __forceinline__ unsigned f2o(float f) {
    unsigned u = __float_as_uint(f);
    return (u & 0x80000000u) ? ~u : (u | 0x80000000u);
}

// ---------- normalize p vectors ----------
__global__ void k_normp(const float* p1, const float* p2, const float* p3, float* pn) {
    const float* ps[3] = {p1, p2, p3};
    const float* p = ps[blockIdx.x];
    int t = threadIdx.x; // 128 threads
    float v = p[t];
    float s = v * v;
    for (int o = 32; o > 0; o >>= 1) s += __shfl_down(s, o);
    __shared__ float ws2[2];
    if ((t & 63) == 0) ws2[t >> 6] = s;
    __syncthreads();
    float tot = ws2[0] + ws2[1];
    pn[blockIdx.x * CF + t] = v / sqrtf(tot);
}

// ---------- GEMM: Y[N][128] = X[N][128] @ W[128][128], f32 ----------
__global__ __launch_bounds__(256, 2) void k_gemm(const float* __restrict__ X,
                                                 const float* __restrict__ W,
                                                 float* __restrict__ Y, int N) {
    __shared__ float xT[32][260];
    __shared__ float Wc[32][128];
    int t = threadIdx.x;
    int cg = t & 15, rg = t >> 4;
    int c0 = cg * 8, r0 = rg * 16;
    int rowBase = blockIdx.x * 256;

    float acc[16][8];
#pragma unroll
    for (int i = 0; i < 16; i++)
#pragma unroll
        for (int j = 0; j < 8; j++) acc[i][j] = 0.f;

    for (int kc = 0; kc < 4; kc++) {
        __syncthreads();
#pragma unroll
        for (int j = 0; j < 8; j++) {
            int id = t + 256 * j;
            int r = id >> 3;
            int k4 = id & 7;
            float4 v = *(const float4*)&X[(rowBase + r) * CF + kc * 32 + k4 * 4];
            int kk = k4 * 4;
            xT[kk + 0][r] = v.x; xT[kk + 1][r] = v.y;
            xT[kk + 2][r] = v.z; xT[kk + 3][r] = v.w;
        }
#pragma unroll
        for (int j = 0; j < 4; j++) {
            int id = t + 256 * j;
            int kk = id >> 5;
            int cc = (id & 31) * 4;
            *(float4*)&Wc[kk][cc] = *(const float4*)&W[(kc * 32 + kk) * CF + cc];
        }
        __syncthreads();
#pragma unroll 4
        for (int kk = 0; kk < 32; kk++) {
            float xr[16];
#pragma unroll
            for (int i = 0; i < 16; i += 4)
                *(float4*)&xr[i] = *(float4*)&xT[kk][r0 + i];
            float wv[8];
            *(float4*)&wv[0] = *(float4*)&Wc[kk][c0];
            *(float4*)&wv[4] = *(float4*)&Wc[kk][c0 + 4];
#pragma unroll
            for (int i = 0; i < 16; i++)
#pragma unroll
                for (int j = 0; j < 8; j++)
                    acc[i][j] = fmaf(xr[i], wv[j], acc[i][j]);
        }
    }
#pragma unroll
    for (int i = 0; i < 16; i++) {
        int r = rowBase + r0 + i;
        *(float4*)&Y[r * CF + c0]     = make_float4(acc[i][0], acc[i][1], acc[i][2], acc[i][3]);
        *(float4*)&Y[r * CF + c0 + 4] = make_float4(acc[i][4], acc[i][5], acc[i][6], acc[i][7]);
    }
}

// ---------- histograms ----------
__global__ void k_hist1(const int* __restrict__ g, const int* __restrict__ dl, int* cnt) {
    int e = blockIdx.x * 256 + threadIdx.x;
    if (e < ET) atomicAdd(&cnt[g[e] * NN0 + dl[e]], 1);
}
__global__ void k_hist2(const int2* __restrict__ edges, const int* pE, int* cnt) {
    int e = blockIdx.x * 256 + threadIdx.x;
    if (e < *pE) atomicAdd(&cnt[edges[e].y], 1);
}

// ---------- exclusive scan (3 kernels), chunk=1024 ----------
__global__ void k_ps1(const int* __restrict__ cnt, int* part) {
    int b = blockIdx.x, t = threadIdx.x;
    int base = b * 1024;
    int s = 0;
    for (int j = t; j < 1024; j += 256) s += cnt[base + j];
    for (int o = 32; o > 0; o >>= 1) s += __shfl_down(s, o);
    __shared__ int sm[4];
    if ((t & 63) == 0) sm[t >> 6] = s;
    __syncthreads();
    if (t == 0) part[b] = sm[0] + sm[1] + sm[2] + sm[3];
}
__global__ void k_ps2(int* part, int nb) {
    if (threadIdx.x == 0) {
        int run = 0;
        for (int i = 0; i < nb; i++) { int v = part[i]; part[i] = run; run += v; }
        part[nb] = run;
    }
}
// emits dis[i] = rsqrt(deg_i) (deg = cnt+1) for the agg pass.
__global__ void k_ps3(const int* __restrict__ cnt, const int* __restrict__ part,
                      int* rowS, int* curs, float* dis, int N) {
    __shared__ int sm[256];
    int b = blockIdx.x, t = threadIdx.x;
    int base = b * 1024;
    int loc[4], cv[4];
    int s = 0;
#pragma unroll
    for (int j = 0; j < 4; j++) { loc[j] = s; cv[j] = cnt[base + t * 4 + j]; s += cv[j]; }
    sm[t] = s;
    __syncthreads();
    for (int o = 1; o < 256; o <<= 1) {
        int u = (t >= o) ? sm[t - o] : 0;
        __syncthreads();
        sm[t] += u;
        __syncthreads();
    }
    int incl = sm[t];
    int thrBase = part[b] + incl - s;
#pragma unroll
    for (int j = 0; j < 4; j++) {
        int idx = base + t * 4 + j;
        rowS[idx] = thrBase + loc[j];
        curs[idx] = thrBase + loc[j];
        if (dis != nullptr) dis[idx] = rsqrtf((float)(cv[j] + 1));
    }
    if (b == gridDim.x - 1 && t == 255) rowS[N] = part[b] + incl;
}

// ---------- CSR fill, XCD-range-partitioned (R6) ----------
__global__ void k_fill1(const int* __restrict__ g, const int* __restrict__ sl,
                        const int* __restrict__ dl, int* curs, int* csrS) {
    int r = blockIdx.x & 7;
    int base = (blockIdx.x >> 3) * 2048;
#pragma unroll
    for (int i = 0; i < 8; i++) {
        int e = base + i * 256 + threadIdx.x;
        int gg = g[e];
        int d = gg * NN0 + dl[e];
        if ((d >> 14) == r) {
            int pos = atomicAdd(&curs[d], 1);
            csrS[pos] = gg * NN0 + sl[e];
        }
    }
}
__global__ void k_fill2(const int2* __restrict__ edges, const int* pE,
                        int* curs, int* csrS, int shift) {
    int r = blockIdx.x & 7;
    int base = (blockIdx.x >> 3) * 2048;
    int E = *pE;
#pragma unroll
    for (int i = 0; i < 8; i++) {
        int e = base + i * 256 + threadIdx.x;
        if (e < E) {
            int2 ed = edges[e];
            if ((ed.y >> shift) == r) {
                int pos = atomicAdd(&curs[ed.y], 1);
                csrS[pos] = ed.x;
            }
        }
    }
}

// ---------- GCN aggregation + fused score ----------
// R10 post-mortem: VGPR_Count=16 proved the allocator serialized the R9 4-deep
// float2 pipeline (needs >=16 regs just for data+addr). R11: paired-edge float4
// rows - 32 lanes/row, lanes 0-31 even edges, 32-63 odd edges (per-lane shfl
// index). One load serves 2 edges: half the loads/shfls per edge guaranteed,
// 2x natural MLP at same register budget; 4-deep unroll = 8 edges in flight.
__global__ void k_agg(const float4* __restrict__ xw, const int* __restrict__ rowS,
                      const int* __restrict__ csrS, const float* __restrict__ dis,
                      const float* __restrict__ bias, const float* __restrict__ pn,
                      float4* __restrict__ h, float* __restrict__ scores, int N) {
    int nb = gridDim.x;
    int bid = blockIdx.x;
    int sb = (bid & 7) * (nb >> 3) + (bid >> 3); // contiguous chunk per XCD
    int d = sb * 4 + (threadIdx.x >> 6);
    int lane = threadIdx.x & 63;
    int hl = lane >> 5;   // 0: even edges, 1: odd edges
    int l = lane & 31;    // float4 slot within row
    int rs = rowS[d], re = rowS[d + 1];
    float4 a = make_float4(0.f, 0.f, 0.f, 0.f);
    for (int j0 = rs; j0 < re; j0 += 64) {
        int myj = j0 + lane;
        int sV = (myj < re) ? csrS[myj] : 0;
        float dV = (myj < re) ? dis[sV] : 0.f;
        int c64 = re - j0; if (c64 > 64) c64 = 64;
        int j = 0;
        for (; j + 8 <= c64; j += 8) {
            int i0 = j + hl, i1 = j + 2 + hl, i2 = j + 4 + hl, i3 = j + 6 + hl;
            int s0 = __shfl(sV, i0), s1 = __shfl(sV, i1);
            int s2 = __shfl(sV, i2), s3 = __shfl(sV, i3);
            float d0 = __shfl(dV, i0), d1 = __shfl(dV, i1);
            float d2 = __shfl(dV, i2), d3 = __shfl(dV, i3);
            float4 v0 = xw[s0 * 32 + l];
            float4 v1 = xw[s1 * 32 + l];
            float4 v2 = xw[s2 * 32 + l];
            float4 v3 = xw[s3 * 32 + l];
            a.x = fmaf(d0, v0.x, a.x); a.y = fmaf(d0, v0.y, a.y);
            a.z = fmaf(d0, v0.z, a.z); a.w = fmaf(d0, v0.w, a.w);
            a.x = fmaf(d1, v1.x, a.x); a.y = fmaf(d1, v1.y, a.y);
            a.z = fmaf(d1, v1.z, a.z); a.w = fmaf(d1, v1.w, a.w);
            a.x = fmaf(d2, v2.x, a.x); a.y = fmaf(d2, v2.y, a.y);
            a.z = fmaf(d2, v2.z, a.z); a.w = fmaf(d2, v2.w, a.w);
            a.x = fmaf(d3, v3.x, a.x); a.y = fmaf(d3, v3.y, a.y);
            a.z = fmaf(d3, v3.z, a.z); a.w = fmaf(d3, v3.w, a.w);
        }
        for (; j < c64; j += 2) {
            int i = j + hl;
            int ic = (i < c64) ? i : (c64 - 1);
            int s = __shfl(sV, ic);
            float dd = __shfl(dV, ic);
            if (i >= c64) dd = 0.f;
            float4 v = xw[s * 32 + l];
            a.x = fmaf(dd, v.x, a.x); a.y = fmaf(dd, v.y, a.y);
            a.z = fmaf(dd, v.z, a.z); a.w = fmaf(dd, v.w, a.w);
        }
    }
    // combine even/odd halves (lanes L and L+32 hold same dims)
    a.x += __shfl_xor(a.x, 32);
    a.y += __shfl_xor(a.y, 32);
    a.z += __shfl_xor(a.z, 32);
    a.w += __shfl_xor(a.w, 32);
    float disd = dis[d];
    float invd = disd * disd; // 1/deg
    float4 xd = xw[d * 32 + l];
    float4 bv = ((const float4*)bias)[l];
    float4 r;
    r.x = disd * a.x + xd.x * invd + bv.x;
    r.y = disd * a.y + xd.y * invd + bv.y;
    r.z = disd * a.z + xd.z * invd + bv.z;
    r.w = disd * a.w + xd.w * invd + bv.w;
    r.x = r.x > 0.f ? r.x : 0.f;
    r.y = r.y > 0.f ? r.y : 0.f;
    r.z = r.z > 0.f ? r.z : 0.f;
    r.w = r.w > 0.f ? r.w : 0.f;
    if (hl == 0) h[d * 32 + l] = r;
    float4 pv = ((const float4*)pn)[l];
    float v = r.x * pv.x + r.y * pv.y + r.z * pv.z + r.w * pv.w;
    for (int o = 32; o > 0; o >>= 1) v += __shfl_down(v, o);
    if (lane == 0) scores[d] = tanhf(0.5f * v); // halves duplicated -> sum is 2x dot
}

// ---------- exact top-k per graph: map[old global] = new local idx or -1 ----------
__global__ void k_topk(const float* __restrict__ scores, int* __restrict__ map, int n, int k) {
    __shared__ unsigned keys[2048];
    __shared__ int sm[256];
    __shared__ int red[4];
    int b = blockIdx.x, t = threadIdx.x;
    const float* sc = scores + b * n;
    int m = n >> 8;

    for (int i = t; i < n; i += 256) keys[i] = f2o(sc[i]);
    __syncthreads();

    unsigned prefix = 0u;
    for (int bit = 31; bit >= 0; bit--) {
        unsigned trial = prefix | (1u << bit);
        int c = 0;
        for (int i = t; i < n; i += 256) c += (keys[i] >= trial) ? 1 : 0;
        for (int o = 32; o > 0; o >>= 1) c += __shfl_down(c, o);
        if ((t & 63) == 0) red[t >> 6] = c;
        __syncthreads();
        int tot = red[0] + red[1] + red[2] + red[3];
        __syncthreads();
        if (tot >= k) prefix = trial;
    }
    unsigned T = prefix;

    int c = 0;
    for (int i = t; i < n; i += 256) c += (keys[i] > T) ? 1 : 0;
    for (int o = 32; o > 0; o >>= 1) c += __shfl_down(c, o);
    if ((t & 63) == 0) red[t >> 6] = c;
    __syncthreads();
    int mEq = k - (red[0] + red[1] + red[2] + red[3]);
    __syncthreads();

    int base = t * m;
    int eqc = 0;
    for (int j = 0; j < m; j++) eqc += (keys[base + j] == T) ? 1 : 0;
    sm[t] = eqc;
    __syncthreads();
    for (int o = 1; o < 256; o <<= 1) {
        int u = (t >= o) ? sm[t - o] : 0;
        __syncthreads();
        sm[t] += u;
        __syncthreads();
    }
    int er = sm[t] - eqc;
    __syncthreads();

    unsigned kb = 0; int kc = 0;
    for (int j = 0; j < m; j++) {
        unsigned ky = keys[base + j];
        bool kp = (ky > T) || (ky == T && er < mEq);
        if (ky == T) er++;
        if (kp) { kb |= (1u << j); kc++; }
    }
    sm[t] = kc;
    __syncthreads();
    for (int o = 1; o < 256; o <<= 1) {
        int u = (t >= o) ? sm[t - o] : 0;
        __syncthreads();
        sm[t] += u;
        __syncthreads();
    }
    int nidx = sm[t] - kc;
    for (int j = 0; j < m; j++) {
        map[b * n + base + j] = ((kb >> j) & 1u) ? nidx++ : -1;
    }
}

// ---------- compact kept nodes: xn[g*k+new] = h[old] * score[old] ----------
__global__ void k_compact(const float* __restrict__ h, const float* __restrict__ scores,
                          const int* __restrict__ map, float* __restrict__ xn,
                          int N, int n, int k) {
    int wid = (blockIdx.x * 256 + threadIdx.x) >> 6;
    int lane = threadIdx.x & 63;
    int mi = map[wid];
    if (mi < 0) return;
    float s = scores[wid];
    int gg = wid / n;
    int dst = (gg * k + mi) * CF;
    xn[dst + lane]      = h[wid * CF + lane] * s;
    xn[dst + 64 + lane] = h[wid * CF + 64 + lane] * s;
}

// ---------- edge remap + compaction, atomic-free two-pass (R6) ----------
__global__ void k_remapA1(const int* __restrict__ g, const int* __restrict__ sl,
                          const int* __restrict__ dl, const int* __restrict__ map,
                          int* __restrict__ wcnt) {
    int e = blockIdx.x * 256 + threadIdx.x;
    int gg = g[e];
    bool valid = (map[gg * NN0 + sl[e]] >= 0) && (map[gg * NN0 + dl[e]] >= 0);
    unsigned long long mask = __ballot(valid);
    if ((threadIdx.x & 63) == 0) wcnt[e >> 6] = __popcll(mask);
}
__global__ void k_remapB1(const int* __restrict__ g, const int* __restrict__ sl,
                          const int* __restrict__ dl, const int* __restrict__ map,
                          const int* __restrict__ wbase, int2* __restrict__ eout,
                          int* __restrict__ pTot, int k) {
    int e = blockIdx.x * 256 + threadIdx.x;
    int lane = threadIdx.x & 63;
    int gg = g[e];
    int ns = map[gg * NN0 + sl[e]];
    int nd = map[gg * NN0 + dl[e]];
    bool valid = (ns >= 0 && nd >= 0);
    unsigned long long mask = __ballot(valid);
    if (valid) {
        int off = __popcll(mask & ((1ull << lane) - 1ull));
        eout[wbase[e >> 6] + off] = make_int2(gg * k + ns, gg * k + nd);
    }
    if (e == 0) pTot[0] = wbase[ET >> 6];
}
__global__ void k_remapA2(const int2* __restrict__ ein, const int* pE,
                          const int* __restrict__ map, int* __restrict__ wcnt) {
    int e = blockIdx.x * 256 + threadIdx.x;
    bool valid = false;
    if (e < *pE) {
        int2 ed = ein[e];
        valid = (map[ed.x] >= 0) && (map[ed.y] >= 0);
    }
    unsigned long long mask = __ballot(valid);
    if ((threadIdx.x & 63) == 0) wcnt[e >> 6] = __popcll(mask);
}
__global__ void k_remapB2(const int2* __restrict__ ein, const int* pE,
                          const int* __restrict__ map, const int* __restrict__ wbase,
                          int2* __restrict__ eout, int* __restrict__ pTot,
                          int n, int k) {
    int e = blockIdx.x * 256 + threadIdx.x;
    int lane = threadIdx.x & 63;
    bool valid = false;
    int gg = 0, ns = 0, nd = 0;
    if (e < *pE) {
        int2 ed = ein[e];
        ns = map[ed.x]; nd = map[ed.y];
        gg = ed.x / n;
        valid = (ns >= 0 && nd >= 0);
    }
    unsigned long long mask = __ballot(valid);
    if (valid) {
        int off = __popcll(mask & ((1ull << lane) - 1ull));
        eout[wbase[e >> 6] + off] = make_int2(gg * k + ns, gg * k + nd);
    }
    if (e == 0) pTot[0] = wbase[ET >> 6];
}

// ---------- fused layer-3 pool ----------
__global__ void k_pool3(const float* __restrict__ h, const float* __restrict__ scores,
                        const int* __restrict__ map, float* __restrict__ pooled) {
    int b = blockIdx.x, cthr = threadIdx.x; // 128 threads
    float acc = 0.f;
    for (int i = 0; i < 512; i++) {
        int gi = b * 512 + i;
        int mi = map[gi];
        if (mi >= 0) acc += h[gi * CF + cthr] * scores[gi];
    }
    pooled[b * CF + cthr] = acc;
}

// ---------- final MLP ----------
__global__ void k_mlp(const float* __restrict__ pooled, const float* __restrict__ Wm,
                      const float* __restrict__ bm, float* __restrict__ out) {
    int b = blockIdx.x, t = threadIdx.x;
    if (t < OUTF) {
        float acc = bm[t];
        for (int c2 = 0; c2 < CF; c2++) acc += pooled[b * CF + c2] * Wm[c2 * OUTF + t];
        out[b * OUTF + t] = acc;
    }
}

extern "C" void kernel_launch(void* const* d_in, const int* in_sizes, int n_in,
                              void* d_out, int out_size, void* d_ws, size_t ws_size,
                              hipStream_t stream) {
    const float* x  = (const float*)d_in[0];
    const int* sl   = (const int*)d_in[1];
    const int* dl   = (const int*)d_in[2];
    const int* g    = (const int*)d_in[3];
    const float* W1 = (const float*)d_in[4];
    const float* b1 = (const float*)d_in[5];
    const float* p1 = (const float*)d_in[6];
    const float* W2 = (const float*)d_in[7];
    const float* b2 = (const float*)d_in[8];
    const float* p2 = (const float*)d_in[9];
    const float* W3 = (const float*)d_in[10];
    const float* b3 = (const float*)d_in[11];
    const float* p3 = (const float*)d_in[12];
    const float* Wm = (const float*)d_in[13];
    const float* bm = (const float*)d_in[14];

    // workspace layout (~145.8 MB total)
    char* ws = (char*)d_ws;
    float* A    = (float*)(ws + 0);            // 64MB
    float* Bb   = (float*)(ws + 67108864ull);  // 64MB
    int*   csrS = (int*)  (ws + 134217728ull); // 8MB
    int*   cnt  = (int*)  (ws + 142606336ull); // 512KB
    int*   rowS = (int*)  (ws + 143130624ull); // 512KB+4
    int*   curs = (int*)  (ws + 143655168ull); // 512KB
    float* scor = (float*)(ws + 144179456ull); // 512KB
    int*   map  = (int*)  (ws + 144703744ull); // 512KB
    float* pn   = (float*)(ws + 145228032ull); // 1.5KB
    float* pool = (float*)(ws + 145230080ull); // 32KB
    int*   ecnt = (int*)  (ws + 145262848ull); // counters
    int*   part = (int*)  (ws + 145263104ull); // scan partials (<=129 ints)
    float* dis  = (float*)(ws + 145264640ull); // 512KB: per-node rsqrt(deg)

    // aliased regions (lifetimes verified):
    int2*  EA  = (int2*)(ws + 33554432ull);              // A[32:48MB]
    int2*  EB  = (int2*)(ws + 67108864ull);              // Bb[0:16MB]
    float* x2  = A;                                      // A[0:32MB]
    float* xw2 = Bb;                                     // Bb[0:32MB]
    float* h2  = A;                                      // A[0:32MB]
    float* x3  = (float*)(ws + 100663296ull);            // Bb[32:48MB]
    float* xw3 = A;                                      // A[0:16MB]
    float* h3  = Bb;                                     // Bb[0:16MB]
    int*   wcnt  = (int*)(ws + 50331648ull);             // A[48:64MB] region
    int*   wbase = (int*)(ws + 50462720ull);

    k_normp<<<3, 128, 0, stream>>>(p1, p2, p3, pn);

    // ================= layer 1 (N=131072, n=2048, k=1024) =================
    k_gemm<<<512, 256, 0, stream>>>(x, W1, A, 131072);
    hipMemsetAsync(cnt, 0, 524288, stream);
    k_hist1<<<8192, 256, 0, stream>>>(g, dl, cnt);
    k_ps1<<<128, 256, 0, stream>>>(cnt, part);
    k_ps2<<<1, 64, 0, stream>>>(part, 128);
    k_ps3<<<128, 256, 0, stream>>>(cnt, part, rowS, curs, dis, 131072);
    k_fill1<<<8192, 256, 0, stream>>>(g, sl, dl, curs, csrS);
    k_agg<<<32768, 256, 0, stream>>>((const float4*)A, rowS, csrS, dis, b1, pn, (float4*)Bb, scor, 131072);
    k_topk<<<64, 256, 0, stream>>>(scor, map, 2048, 1024);
    k_compact<<<32768, 256, 0, stream>>>(Bb, scor, map, x2, 131072, 2048, 1024);
    k_remapA1<<<8192, 256, 0, stream>>>(g, sl, dl, map, wcnt);
    k_ps1<<<32, 256, 0, stream>>>(wcnt, part);
    k_ps2<<<1, 64, 0, stream>>>(part, 32);
    k_ps3<<<32, 256, 0, stream>>>(wcnt, part, wbase, wbase, nullptr, 32768);
    k_remapB1<<<8192, 256, 0, stream>>>(g, sl, dl, map, wbase, EA, &ecnt[0], 1024);

    // ================= layer 2 (N=65536, n=1024, k=512) =================
    k_gemm<<<256, 256, 0, stream>>>(x2, W2, xw2, 65536);
    hipMemsetAsync(cnt, 0, 262144, stream);
    k_hist2<<<8192, 256, 0, stream>>>(EA, &ecnt[0], cnt);
    k_ps1<<<64, 256, 0, stream>>>(cnt, part);
    k_ps2<<<1, 64, 0, stream>>>(part, 64);
    k_ps3<<<64, 256, 0, stream>>>(cnt, part, rowS, curs, dis, 65536);
    k_fill2<<<8192, 256, 0, stream>>>(EA, &ecnt[0], curs, csrS, 13);
    k_agg<<<16384, 256, 0, stream>>>((const float4*)xw2, rowS, csrS, dis, b2, pn + 128, (float4*)h2, scor, 65536);
    k_topk<<<64, 256, 0, stream>>>(scor, map, 1024, 512);
    k_compact<<<16384, 256, 0, stream>>>(h2, scor, map, x3, 65536, 1024, 512);
    k_remapA2<<<8192, 256, 0, stream>>>(EA, &ecnt[0], map, wcnt);
    k_ps1<<<32, 256, 0, stream>>>(wcnt, part);
    k_ps2<<<1, 64, 0, stream>>>(part, 32);
    k_ps3<<<32, 256, 0, stream>>>(wcnt, part, wbase, wbase, nullptr, 32768);
    k_remapB2<<<8192, 256, 0, stream>>>(EA, &ecnt[0], map, wbase, EB, &ecnt[1], 1024, 512);

    // ================= layer 3 (N=32768, n=512, k=256) =================
    k_gemm<<<128, 256, 0, stream>>>(x3, W3, xw3, 32768);
    hipMemsetAsync(cnt, 0, 131072, stream);
    k_hist2<<<8192, 256, 0, stream>>>(EB, &ecnt[1], cnt);
    k_ps1<<<32, 256, 0, stream>>>(cnt, part);
    k_ps2<<<1, 64, 0, stream>>>(part, 32);
    k_ps3<<<32, 256, 0, stream>>>(cnt, part, rowS, curs, dis, 32768);
    k_fill2<<<8192, 256, 0, stream>>>(EB, &ecnt[1], curs, csrS, 12);
    k_agg<<<8192, 256, 0, stream>>>((const float4*)xw3, rowS, csrS, dis, b3, pn + 256, (float4*)h3, scor, 32768);
    k_topk<<<64, 256, 0, stream>>>(scor, map, 512, 256);
    k_pool3<<<64, 128, 0, stream>>>(h3, scor, map, pool);
    k_mlp<<<64, 64, 0, stream>>>(pool, Wm, bm, (float*)d_out);
}